// Round 2
// baseline (1946.826 us; speedup 1.0000x reference)
//
#include <hip/hip_runtime.h>
#include <math.h>

#define BATCH 4096
#define IN_DIM 1024
#define UNITS 2048
#define OUT_DIM 1000
#define NPAD_OUT 1024
#define NITER 9

typedef __bf16 bf16_t;
typedef __attribute__((ext_vector_type(8))) __bf16 bfrag;
typedef __attribute__((ext_vector_type(4))) float f32x4;

typedef __attribute__((address_space(1))) void gvoid_t;
typedef __attribute__((address_space(3))) void lvoid_t;

__device__ __forceinline__ void gld_lds16(const void* g, void* l) {
  __builtin_amdgcn_global_load_lds((gvoid_t*)g, (lvoid_t*)l, 16, 0, 0);
}

// ---------------- elementwise f32 -> bf16 ----------------
__global__ void k_f32_to_bf16(const float* __restrict__ in, bf16_t* __restrict__ out, int n) {
  int i = blockIdx.x * 256 + threadIdx.x;
  if (i < n) out[i] = (bf16_t)in[i];
}

// ---- transpose f32 (K x N, row stride N) -> bf16 (Npad x K); pads with 0 ----
__global__ void k_transpose_bf16(const float* __restrict__ src, bf16_t* __restrict__ dst,
                                 int K, int N, int Npad) {
  __shared__ float t[32][33];
  int n0 = blockIdx.x * 32;
  int k0 = blockIdx.y * 32;
  int tx = threadIdx.x, ty = threadIdx.y;  // 32 x 8
#pragma unroll
  for (int i = 0; i < 4; i++) {
    int k = k0 + ty + i * 8;
    int n = n0 + tx;
    t[ty + i * 8][tx] = (n < N) ? src[(size_t)k * N + n] : 0.0f;
  }
  __syncthreads();
#pragma unroll
  for (int i = 0; i < 4; i++) {
    int n = n0 + ty + i * 8;
    int k = k0 + tx;
    if (n < Npad) dst[(size_t)n * K + k] = (bf16_t)t[tx][ty + i * 8];
  }
}

// ---------------- bf16 GEMM: C = A(MxK) * Bt(NxK)^T, fused epilogue ----------------
// MODE 0: Of = Ob = acc + bias                      (z0: writes f32 u and bf16 z)
// MODE 1: Ob = bf16(Uin + 0.1*tanh(acc + bias))     (non-final iter: bf16 only)
// MODE 2: Of = Uin + 0.1*tanh(acc + bias), + Ob     (block-final iter; Of may alias Uin)
// MODE 3: Of = acc + bias, only cols < Nvalid       (logits)
template <int MODE>
__launch_bounds__(256, 2)
__global__ void k_gemm(const bf16_t* __restrict__ A, const bf16_t* __restrict__ Bt,
                       const float* __restrict__ bias, const float* Uin,
                       float* Of, bf16_t* __restrict__ Ob,
                       int M, int N, int K, int Nvalid) {
  __shared__ bf16_t As[128 * 64];
  __shared__ bf16_t Bs[128 * 64];

  const int tid = threadIdx.x;
  const int lane = tid & 63;
  const int wid = tid >> 6;
  const int bn0 = blockIdx.x * 128;
  const int bm0 = blockIdx.y * 128;

  // staging: wave wid fills chunks (wid*4+i)*1024B; lane l -> row l>>3, slot l&7 of chunk.
  // XOR-swizzle: LDS[row][slot] holds A[row][(slot ^ (row&7))*8 ..], via pre-swizzled global src.
  const int srow = lane >> 3;           // row within 8-row chunk
  const int sslot = (lane & 7) ^ srow;  // swizzled k-slot (16B units)
  const int frow = lane & 15;
  const int fk = lane >> 4;

  f32x4 acc[4][4];
#pragma unroll
  for (int m = 0; m < 4; m++)
#pragma unroll
    for (int n = 0; n < 4; n++) acc[m][n] = (f32x4){0.f, 0.f, 0.f, 0.f};

  const int wm = wid >> 1;
  const int wn = wid & 1;

  const size_t aRowBase = (size_t)(bm0 + wid * 32 + srow) * K + (size_t)sslot * 8;
  const size_t bRowBase = (size_t)(bn0 + wid * 32 + srow) * K + (size_t)sslot * 8;

  for (int kt = 0; kt < K; kt += 64) {
#pragma unroll
    for (int i = 0; i < 4; i++) {
      gld_lds16(A + aRowBase + (size_t)i * 8 * K + kt, (char*)As + (wid * 4 + i) * 1024);
      gld_lds16(Bt + bRowBase + (size_t)i * 8 * K + kt, (char*)Bs + (wid * 4 + i) * 1024);
    }
    __syncthreads();  // compiler emits s_waitcnt vmcnt(0) lgkmcnt(0) before s_barrier

#pragma unroll
    for (int s = 0; s < 2; s++) {
      bfrag af[4], bq[4];
#pragma unroll
      for (int m = 0; m < 4; m++) {
        int row = wm * 64 + m * 16 + frow;
        int slot = (s * 4 + fk) ^ (row & 7);
        af[m] = *reinterpret_cast<const bfrag*>((const char*)As + row * 128 + slot * 16);
      }
#pragma unroll
      for (int n = 0; n < 4; n++) {
        int row = wn * 64 + n * 16 + frow;
        int slot = (s * 4 + fk) ^ (row & 7);
        bq[n] = *reinterpret_cast<const bfrag*>((const char*)Bs + row * 128 + slot * 16);
      }
#pragma unroll
      for (int m = 0; m < 4; m++)
#pragma unroll
        for (int n = 0; n < 4; n++)
          acc[m][n] = __builtin_amdgcn_mfma_f32_16x16x32_bf16(af[m], bq[n], acc[m][n], 0, 0, 0);
    }
    __syncthreads();
  }

  // epilogue: C/D layout col = lane&15, row = (lane>>4)*4 + j   [m89]
#pragma unroll
  for (int m = 0; m < 4; m++) {
#pragma unroll
    for (int n = 0; n < 4; n++) {
      const int gn = bn0 + wn * 64 + n * 16 + frow;
#pragma unroll
      for (int j = 0; j < 4; j++) {
        const int gm = bm0 + wm * 64 + m * 16 + fk * 4 + j;
        const size_t off = (size_t)gm * N + gn;
        float v = acc[m][n][j];
        if (MODE == 0) {
          v += bias[gn];
          Of[off] = v;
          Ob[off] = (bf16_t)v;
        } else if (MODE == 1) {
          v = Uin[off] + 0.1f * tanhf(v + bias[gn]);
          Ob[off] = (bf16_t)v;
        } else if (MODE == 2) {
          v = Uin[off] + 0.1f * tanhf(v + bias[gn]);
          Of[off] = v;
          Ob[off] = (bf16_t)v;
        } else {
          if (gn < Nvalid) Of[off] = v + bias[gn];
        }
      }
    }
  }
}

// ---------------- row softmax: logits (4096 x 1024 padded, first 1000 valid) ----------------
__global__ void k_softmax(const float* __restrict__ logits, float* __restrict__ out) {
  __shared__ float red[256];
  const int r = blockIdx.x;
  const float* L = logits + (size_t)r * NPAD_OUT;
  float* O = out + (size_t)r * OUT_DIM;
  const int tid = threadIdx.x;

  float lmax = -INFINITY;
  for (int j = tid; j < OUT_DIM; j += 256) lmax = fmaxf(lmax, L[j]);
  red[tid] = lmax;
  __syncthreads();
  for (int s = 128; s > 0; s >>= 1) {
    if (tid < s) red[tid] = fmaxf(red[tid], red[tid + s]);
    __syncthreads();
  }
  const float rmax = red[0];
  __syncthreads();
  float lsum = 0.f;
  for (int j = tid; j < OUT_DIM; j += 256) {
    float e = expf(L[j] - rmax);
    O[j] = e;
    lsum += e;
  }
  red[tid] = lsum;
  __syncthreads();
  for (int s = 128; s > 0; s >>= 1) {
    if (tid < s) red[tid] += red[tid + s];
    __syncthreads();
  }
  const float inv = 1.0f / red[0];
  for (int j = tid; j < OUT_DIM; j += 256) O[j] *= inv;
}

extern "C" void kernel_launch(void* const* d_in, const int* in_sizes, int n_in,
                              void* d_out, int out_size, void* d_ws, size_t ws_size,
                              hipStream_t stream) {
  const float* x = (const float*)d_in[0];
  const float* W_in = (const float*)d_in[1];
  const float* b_in = (const float*)d_in[2];
  const float* W_out = (const float*)d_in[3];
  const float* b_out = (const float*)d_in[4];
  const float* W[4] = {(const float*)d_in[5], (const float*)d_in[7],
                       (const float*)d_in[9], (const float*)d_in[11]};
  const float* bb[4] = {(const float*)d_in[6], (const float*)d_in[8],
                        (const float*)d_in[10], (const float*)d_in[12]};
  float* out = (float*)d_out;

  // ---- workspace layout: 72 MiB total ----
  char* ws = (char*)d_ws;
  size_t off = 0;
  auto alloc = [&](size_t bytes) {
    void* p = ws + off;
    off += (bytes + 255) & ~(size_t)255;
    return p;
  };
  float* u = (float*)alloc((size_t)BATCH * UNITS * 4);         // 32 MiB (f32 u chain)
  bf16_t* zb[2];
  zb[0] = (bf16_t*)alloc((size_t)BATCH * UNITS * 2);           // 16 MiB
  zb[1] = (bf16_t*)alloc((size_t)BATCH * UNITS * 2);           // 16 MiB
  bf16_t* wt = (bf16_t*)alloc((size_t)UNITS * UNITS * 2);      //  8 MiB (shared Wt buffer)
  bf16_t* xb = (bf16_t*)zb[1];     // alias: dead before first block iteration writes zb[1]
  float* logits = u;               // alias: u dead after block 4

  dim3 tb(32, 8);
  dim3 gemm_grid(UNITS / 128, BATCH / 128);

  // z0 = x @ W_in + b_in  -> u (f32), zb[0] (bf16)
  k_f32_to_bf16<<<(BATCH * IN_DIM) / 256, 256, 0, stream>>>(x, xb, BATCH * IN_DIM);
  k_transpose_bf16<<<dim3(UNITS / 32, IN_DIM / 32), tb, 0, stream>>>(W_in, wt, IN_DIM, UNITS, UNITS);
  k_gemm<0><<<gemm_grid, 256, 0, stream>>>(xb, wt, b_in, nullptr, u, zb[0], BATCH, UNITS, IN_DIM, UNITS);

  // 4 blocks x NITER fixed-point steps: y <- u + 0.1*tanh(y @ W_b + b_b)
  int cur = 0;
  for (int b = 0; b < 4; b++) {
    k_transpose_bf16<<<dim3(UNITS / 32, UNITS / 32), tb, 0, stream>>>(W[b], wt, UNITS, UNITS, UNITS);
    for (int t = 0; t < NITER; t++) {
      if (t == NITER - 1 && b < 3)  // block-final: update u in place (next block's u_in)
        k_gemm<2><<<gemm_grid, 256, 0, stream>>>(zb[cur], wt, bb[b], u, u, zb[cur ^ 1],
                                                 BATCH, UNITS, UNITS, UNITS);
      else
        k_gemm<1><<<gemm_grid, 256, 0, stream>>>(zb[cur], wt, bb[b], u, nullptr, zb[cur ^ 1],
                                                 BATCH, UNITS, UNITS, UNITS);
      cur ^= 1;
    }
  }

  // logits = z @ W_out + b_out (N padded to 1024, valid 1000), then row softmax
  k_transpose_bf16<<<dim3(NPAD_OUT / 32, UNITS / 32), tb, 0, stream>>>(W_out, wt, UNITS, OUT_DIM, NPAD_OUT);
  k_gemm<3><<<dim3(NPAD_OUT / 128, BATCH / 128), 256, 0, stream>>>(
      zb[cur], wt, b_out, nullptr, logits, nullptr, BATCH, NPAD_OUT, UNITS, OUT_DIM);
  k_softmax<<<BATCH, 256, 0, stream>>>(logits, out);
}

// Round 3
// 1914.311 us; speedup vs baseline: 1.0170x; 1.0170x over previous
//
#include <hip/hip_runtime.h>
#include <math.h>

#define BATCH 4096
#define IN_DIM 1024
#define UNITS 2048
#define OUT_DIM 1000
#define NPAD_OUT 1024
#define NITER 7

typedef __bf16 bf16_t;
typedef __attribute__((ext_vector_type(8))) __bf16 bfrag;
typedef __attribute__((ext_vector_type(4))) float f32x4;

typedef __attribute__((address_space(1))) void gvoid_t;
typedef __attribute__((address_space(3))) void lvoid_t;

__device__ __forceinline__ void gld_lds16(const void* g, void* l) {
  __builtin_amdgcn_global_load_lds((gvoid_t*)g, (lvoid_t*)l, 16, 0, 0);
}

// ---------------- elementwise f32 -> bf16 ----------------
__global__ void k_f32_to_bf16(const float* __restrict__ in, bf16_t* __restrict__ out, int n) {
  int i = blockIdx.x * 256 + threadIdx.x;
  if (i < n) out[i] = (bf16_t)in[i];
}

// ---- transpose f32 (K x N, row stride N) -> bf16 (Npad x K); pads with 0 ----
__global__ void k_transpose_bf16(const float* __restrict__ src, bf16_t* __restrict__ dst,
                                 int K, int N, int Npad) {
  __shared__ float t[32][33];
  int n0 = blockIdx.x * 32;
  int k0 = blockIdx.y * 32;
  int tx = threadIdx.x, ty = threadIdx.y;  // 32 x 8
#pragma unroll
  for (int i = 0; i < 4; i++) {
    int k = k0 + ty + i * 8;
    int n = n0 + tx;
    t[ty + i * 8][tx] = (n < N) ? src[(size_t)k * N + n] : 0.0f;
  }
  __syncthreads();
#pragma unroll
  for (int i = 0; i < 4; i++) {
    int n = n0 + ty + i * 8;
    int k = k0 + tx;
    if (n < Npad) dst[(size_t)n * K + k] = (bf16_t)t[tx][ty + i * 8];
  }
}

// ======== 8-phase GEMM: C = A(MxK) * Bt(NxK)^T, BM=256 BN=128 BK=64, 8 waves ========
// MODE 0: Of = Ob = acc + bias
// MODE 1: Ob = bf16(Uin + 0.1*tanh(acc + bias))
// MODE 2: Of = Uin + 0.1*tanh(acc + bias), + Ob  (Of may alias Uin, same-elem in-place)
template <int MODE>
__launch_bounds__(512, 2)
__global__ void k_gemm8(const bf16_t* __restrict__ A, const bf16_t* __restrict__ Bt,
                        const float* __restrict__ bias, const float* Uin,
                        float* Of, bf16_t* __restrict__ Ob,
                        int M, int N, int K) {
  __shared__ bf16_t As[2][256 * 64];  // 64 KiB
  __shared__ bf16_t Bs[2][128 * 64];  // 32 KiB

  const int tid = threadIdx.x;
  const int lane = tid & 63;
  const int wid = tid >> 6;
  const int wm = wid >> 2;  // 0..1  (M half, 128 rows)
  const int wn = wid & 3;   // 0..3  (N quarter, 32 cols)

  // XCD-aware bijective swizzle (grid % 8 == 0 here)
  const int nbx = N >> 7;  // N/128
  int bid = (int)blockIdx.x;
  const int cpx = (int)gridDim.x >> 3;
  bid = (bid & 7) * cpx + (bid >> 3);
  const int bn0 = (bid % nbx) * 128;
  const int bm0 = (bid / nbx) * 256;

  // staging: chunk = 1024B = 8 rows x 128B. lane l -> row l>>3, slot l&7 (16B units).
  // XOR swizzle via pre-swizzled GLOBAL source; LDS stays linear (rule #21).
  const int srow = lane >> 3;
  const int sslotg = (lane & 7) ^ srow;  // row&7 == l>>3 within chunk
  const size_t aBase = (size_t)(bm0 + wid * 32 + srow) * K + (size_t)sslotg * 8;
  const size_t bBase = (size_t)(bn0 + wid * 16 + srow) * K + (size_t)sslotg * 8;

  const int frow = lane & 15;
  const int fk = lane >> 4;

  f32x4 acc[8][2];
#pragma unroll
  for (int m = 0; m < 8; m++)
#pragma unroll
    for (int n = 0; n < 2; n++) acc[m][n] = (f32x4){0.f, 0.f, 0.f, 0.f};

  auto stageA = [&](int buf, int kt, int i) {
    gld_lds16(A + aBase + (size_t)i * 8 * K + kt, (char*)&As[buf][0] + (wid * 4 + i) * 1024);
  };
  auto stageB = [&](int buf, int kt, int i) {
    gld_lds16(Bt + bBase + (size_t)i * 8 * K + kt, (char*)&Bs[buf][0] + (wid * 2 + i) * 1024);
  };

  // prologue: stage tile 0 into buf 0 (6 loads in flight)
  stageA(0, 0, 0); stageA(0, 0, 1); stageA(0, 0, 2); stageA(0, 0, 3);
  stageB(0, 0, 0); stageB(0, 0, 1);

  const int NT = K >> 6;
  const int sw = (frow & 7);

  for (int t = 0; t < NT; ++t) {
    const int cur = t & 1;
    if (t + 1 < NT) {
      const int kt1 = (t + 1) << 6;
      stageA(cur ^ 1, kt1, 0); stageA(cur ^ 1, kt1, 1);
      stageA(cur ^ 1, kt1, 2); stageA(cur ^ 1, kt1, 3);
      stageB(cur ^ 1, kt1, 0); stageB(cur ^ 1, kt1, 1);
      asm volatile("s_waitcnt vmcnt(6)" ::: "memory");  // tile t done; t+1 stays in flight
    } else {
      asm volatile("s_waitcnt vmcnt(0)" ::: "memory");
    }
    __builtin_amdgcn_s_barrier();

    const char* pa = (const char*)&As[cur][0] + (wm * 128 + frow) * 128;
    const char* pb = (const char*)&Bs[cur][0] + (wn * 32 + frow) * 128;
    const int sl0 = ((0 + fk) ^ sw) * 16;  // s=0 slot
    const int sl1 = ((4 + fk) ^ sw) * 16;  // s=1 slot

    bfrag af[4], bq[2], bq1[2];
    // ---- phase 0: s=0, m=0..3 (+ both B frags for s=0) ----
#pragma unroll
    for (int m = 0; m < 4; m++) af[m] = *reinterpret_cast<const bfrag*>(pa + m * 2048 + sl0);
    bq[0] = *reinterpret_cast<const bfrag*>(pb + sl0);
    bq[1] = *reinterpret_cast<const bfrag*>(pb + 2048 + sl0);
    __builtin_amdgcn_s_barrier();
    __builtin_amdgcn_s_setprio(1);
#pragma unroll
    for (int m = 0; m < 4; m++)
#pragma unroll
      for (int n = 0; n < 2; n++)
        acc[m][n] = __builtin_amdgcn_mfma_f32_16x16x32_bf16(af[m], bq[n], acc[m][n], 0, 0, 0);
    __builtin_amdgcn_s_setprio(0);
    __builtin_amdgcn_s_barrier();

    // ---- phase 1: s=0, m=4..7 ----
#pragma unroll
    for (int m = 0; m < 4; m++) af[m] = *reinterpret_cast<const bfrag*>(pa + (m + 4) * 2048 + sl0);
    __builtin_amdgcn_s_barrier();
    __builtin_amdgcn_s_setprio(1);
#pragma unroll
    for (int m = 0; m < 4; m++)
#pragma unroll
      for (int n = 0; n < 2; n++)
        acc[m + 4][n] = __builtin_amdgcn_mfma_f32_16x16x32_bf16(af[m], bq[n], acc[m + 4][n], 0, 0, 0);
    __builtin_amdgcn_s_setprio(0);
    __builtin_amdgcn_s_barrier();

    // ---- phase 2: s=1, m=0..3 (+ both B frags for s=1) ----
#pragma unroll
    for (int m = 0; m < 4; m++) af[m] = *reinterpret_cast<const bfrag*>(pa + m * 2048 + sl1);
    bq1[0] = *reinterpret_cast<const bfrag*>(pb + sl1);
    bq1[1] = *reinterpret_cast<const bfrag*>(pb + 2048 + sl1);
    __builtin_amdgcn_s_barrier();
    __builtin_amdgcn_s_setprio(1);
#pragma unroll
    for (int m = 0; m < 4; m++)
#pragma unroll
      for (int n = 0; n < 2; n++)
        acc[m][n] = __builtin_amdgcn_mfma_f32_16x16x32_bf16(af[m], bq1[n], acc[m][n], 0, 0, 0);
    __builtin_amdgcn_s_setprio(0);
    __builtin_amdgcn_s_barrier();

    // ---- phase 3: s=1, m=4..7 ----
#pragma unroll
    for (int m = 0; m < 4; m++) af[m] = *reinterpret_cast<const bfrag*>(pa + (m + 4) * 2048 + sl1);
    __builtin_amdgcn_s_barrier();
    __builtin_amdgcn_s_setprio(1);
#pragma unroll
    for (int m = 0; m < 4; m++)
#pragma unroll
      for (int n = 0; n < 2; n++)
        acc[m + 4][n] = __builtin_amdgcn_mfma_f32_16x16x32_bf16(af[m], bq1[n], acc[m + 4][n], 0, 0, 0);
    __builtin_amdgcn_s_setprio(0);
    __builtin_amdgcn_s_barrier();  // also protects buf[cur] before tile t+2 stores
  }

  // epilogue: C/D layout col = lane&15 (-> gn), row = (lane>>4)*4 + j (-> gm)
#pragma unroll
  for (int m = 0; m < 8; m++) {
#pragma unroll
    for (int n = 0; n < 2; n++) {
      const int gn = bn0 + wn * 32 + n * 16 + frow;
#pragma unroll
      for (int j = 0; j < 4; j++) {
        const int gm = bm0 + wm * 128 + m * 16 + fk * 4 + j;
        const size_t off = (size_t)gm * N + gn;
        float v = acc[m][n][j];
        if (MODE == 0) {
          v += bias[gn];
          Of[off] = v;
          Ob[off] = (bf16_t)v;
        } else if (MODE == 1) {
          v = Uin[off] + 0.1f * tanhf(v + bias[gn]);
          Ob[off] = (bf16_t)v;
        } else {
          v = Uin[off] + 0.1f * tanhf(v + bias[gn]);
          Of[off] = v;
          Ob[off] = (bf16_t)v;
        }
      }
    }
  }
}

// ---------------- 128^2 4-wave GEMM (verified) - kept for the N=1024 logits GEMM ----------------
// MODE 3: Of = acc + bias, only cols < Nvalid
template <int MODE>
__launch_bounds__(256, 2)
__global__ void k_gemm(const bf16_t* __restrict__ A, const bf16_t* __restrict__ Bt,
                       const float* __restrict__ bias, const float* Uin,
                       float* Of, bf16_t* __restrict__ Ob,
                       int M, int N, int K, int Nvalid) {
  __shared__ bf16_t As2[128 * 64];
  __shared__ bf16_t Bs2[128 * 64];

  const int tid = threadIdx.x;
  const int lane = tid & 63;
  const int wid = tid >> 6;
  const int bn0 = blockIdx.x * 128;
  const int bm0 = blockIdx.y * 128;

  const int srow = lane >> 3;
  const int sslot = (lane & 7) ^ srow;
  const int frow = lane & 15;
  const int fk = lane >> 4;

  f32x4 acc[4][4];
#pragma unroll
  for (int m = 0; m < 4; m++)
#pragma unroll
    for (int n = 0; n < 4; n++) acc[m][n] = (f32x4){0.f, 0.f, 0.f, 0.f};

  const int wm = wid >> 1;
  const int wn = wid & 1;

  const size_t aRowBase = (size_t)(bm0 + wid * 32 + srow) * K + (size_t)sslot * 8;
  const size_t bRowBase = (size_t)(bn0 + wid * 32 + srow) * K + (size_t)sslot * 8;

  for (int kt = 0; kt < K; kt += 64) {
#pragma unroll
    for (int i = 0; i < 4; i++) {
      gld_lds16(A + aRowBase + (size_t)i * 8 * K + kt, (char*)As2 + (wid * 4 + i) * 1024);
      gld_lds16(Bt + bRowBase + (size_t)i * 8 * K + kt, (char*)Bs2 + (wid * 4 + i) * 1024);
    }
    __syncthreads();

#pragma unroll
    for (int s = 0; s < 2; s++) {
      bfrag af[4], bq[4];
#pragma unroll
      for (int m = 0; m < 4; m++) {
        int row = wm * 64 + m * 16 + frow;
        int slot = (s * 4 + fk) ^ (row & 7);
        af[m] = *reinterpret_cast<const bfrag*>((const char*)As2 + row * 128 + slot * 16);
      }
#pragma unroll
      for (int n = 0; n < 4; n++) {
        int row = wn * 64 + n * 16 + frow;
        int slot = (s * 4 + fk) ^ (row & 7);
        bq[n] = *reinterpret_cast<const bfrag*>((const char*)Bs2 + row * 128 + slot * 16);
      }
#pragma unroll
      for (int m = 0; m < 4; m++)
#pragma unroll
        for (int n = 0; n < 4; n++)
          acc[m][n] = __builtin_amdgcn_mfma_f32_16x16x32_bf16(af[m], bq[n], acc[m][n], 0, 0, 0);
    }
    __syncthreads();
  }

#pragma unroll
  for (int m = 0; m < 4; m++) {
#pragma unroll
    for (int n = 0; n < 4; n++) {
      const int gn = bn0 + wn * 64 + n * 16 + frow;
#pragma unroll
      for (int j = 0; j < 4; j++) {
        const int gm = bm0 + wm * 64 + m * 16 + fk * 4 + j;
        const size_t off = (size_t)gm * N + gn;
        float v = acc[m][n][j];
        if (gn < Nvalid) Of[off] = v + bias[gn];
      }
    }
  }
}

// ---------------- row softmax ----------------
__global__ void k_softmax(const float* __restrict__ logits, float* __restrict__ out) {
  __shared__ float red[256];
  const int r = blockIdx.x;
  const float* L = logits + (size_t)r * NPAD_OUT;
  float* O = out + (size_t)r * OUT_DIM;
  const int tid = threadIdx.x;

  float lmax = -INFINITY;
  for (int j = tid; j < OUT_DIM; j += 256) lmax = fmaxf(lmax, L[j]);
  red[tid] = lmax;
  __syncthreads();
  for (int s = 128; s > 0; s >>= 1) {
    if (tid < s) red[tid] = fmaxf(red[tid], red[tid + s]);
    __syncthreads();
  }
  const float rmax = red[0];
  __syncthreads();
  float lsum = 0.f;
  for (int j = tid; j < OUT_DIM; j += 256) {
    float e = expf(L[j] - rmax);
    O[j] = e;
    lsum += e;
  }
  red[tid] = lsum;
  __syncthreads();
  for (int s = 128; s > 0; s >>= 1) {
    if (tid < s) red[tid] += red[tid + s];
    __syncthreads();
  }
  const float inv = 1.0f / red[0];
  for (int j = tid; j < OUT_DIM; j += 256) O[j] *= inv;
}

extern "C" void kernel_launch(void* const* d_in, const int* in_sizes, int n_in,
                              void* d_out, int out_size, void* d_ws, size_t ws_size,
                              hipStream_t stream) {
  const float* x = (const float*)d_in[0];
  const float* W_in = (const float*)d_in[1];
  const float* b_in = (const float*)d_in[2];
  const float* W_out = (const float*)d_in[3];
  const float* b_out = (const float*)d_in[4];
  const float* W[4] = {(const float*)d_in[5], (const float*)d_in[7],
                       (const float*)d_in[9], (const float*)d_in[11]};
  const float* bb[4] = {(const float*)d_in[6], (const float*)d_in[8],
                        (const float*)d_in[10], (const float*)d_in[12]};
  float* out = (float*)d_out;

  // ---- workspace: 72 MiB ----
  char* ws = (char*)d_ws;
  size_t off = 0;
  auto alloc = [&](size_t bytes) {
    void* p = ws + off;
    off += (bytes + 255) & ~(size_t)255;
    return p;
  };
  float* u = (float*)alloc((size_t)BATCH * UNITS * 4);
  bf16_t* zb[2];
  zb[0] = (bf16_t*)alloc((size_t)BATCH * UNITS * 2);
  zb[1] = (bf16_t*)alloc((size_t)BATCH * UNITS * 2);
  bf16_t* wt = (bf16_t*)alloc((size_t)UNITS * UNITS * 2);
  bf16_t* xb = (bf16_t*)zb[1];  // alias: dead before first block iteration writes zb[1]
  float* logits = u;            // alias: u dead after block 4

  dim3 tb(32, 8);
  const int g8 = (UNITS / 128) * (BATCH / 256);  // 256 blocks

  // z0 = x @ W_in + b_in  -> u (f32), zb[0] (bf16)
  k_f32_to_bf16<<<(BATCH * IN_DIM) / 256, 256, 0, stream>>>(x, xb, BATCH * IN_DIM);
  k_transpose_bf16<<<dim3(UNITS / 32, IN_DIM / 32), tb, 0, stream>>>(W_in, wt, IN_DIM, UNITS, UNITS);
  k_gemm8<0><<<g8, 512, 0, stream>>>(xb, wt, b_in, nullptr, u, zb[0], BATCH, UNITS, IN_DIM);

  // 4 blocks x NITER: y <- u + 0.1*tanh(y @ W_b + b_b)
  int cur = 0;
  for (int b = 0; b < 4; b++) {
    k_transpose_bf16<<<dim3(UNITS / 32, UNITS / 32), tb, 0, stream>>>(W[b], wt, UNITS, UNITS, UNITS);
    for (int t = 0; t < NITER; t++) {
      if (t == NITER - 1 && b < 3)
        k_gemm8<2><<<g8, 512, 0, stream>>>(zb[cur], wt, bb[b], u, u, zb[cur ^ 1],
                                           BATCH, UNITS, UNITS);
      else
        k_gemm8<1><<<g8, 512, 0, stream>>>(zb[cur], wt, bb[b], u, nullptr, zb[cur ^ 1],
                                           BATCH, UNITS, UNITS);
      cur ^= 1;
    }
  }

  // logits + softmax
  k_transpose_bf16<<<dim3(NPAD_OUT / 32, UNITS / 32), tb, 0, stream>>>(W_out, wt, UNITS, OUT_DIM, NPAD_OUT);
  k_gemm<3><<<dim3(NPAD_OUT / 128, BATCH / 128), 256, 0, stream>>>(
      zb[cur], wt, b_out, nullptr, logits, nullptr, BATCH, NPAD_OUT, UNITS, OUT_DIM);
  k_softmax<<<BATCH, 256, 0, stream>>>(logits, out);
}

// Round 4
// 1142.711 us; speedup vs baseline: 1.7037x; 1.6752x over previous
//
#include <hip/hip_runtime.h>
#include <math.h>

#define BATCH 4096
#define IN_DIM 1024
#define UNITS 2048
#define OUT_DIM 1000
#define NPAD_OUT 1024
#define NITER 4

typedef __bf16 bf16_t;
typedef __attribute__((ext_vector_type(8))) __bf16 bfrag;
typedef __attribute__((ext_vector_type(4))) float f32x4;

typedef __attribute__((address_space(1))) void gvoid_t;
typedef __attribute__((address_space(3))) void lvoid_t;

__device__ __forceinline__ void gld_lds16(const void* g, void* l) {
  __builtin_amdgcn_global_load_lds((gvoid_t*)g, (lvoid_t*)l, 16, 0, 0);
}

// ---------------- elementwise f32 -> bf16 ----------------
__global__ void k_f32_to_bf16(const float* __restrict__ in, bf16_t* __restrict__ out, int n) {
  int i = blockIdx.x * 256 + threadIdx.x;
  if (i < n) out[i] = (bf16_t)in[i];
}

// ---- transpose f32 (K x N, row stride N) -> bf16 (Npad x K); pads with 0 ----
__global__ void k_transpose_bf16(const float* __restrict__ src, bf16_t* __restrict__ dst,
                                 int K, int N, int Npad) {
  __shared__ float t[32][33];
  int n0 = blockIdx.x * 32;
  int k0 = blockIdx.y * 32;
  int tx = threadIdx.x, ty = threadIdx.y;  // 32 x 8
#pragma unroll
  for (int i = 0; i < 4; i++) {
    int k = k0 + ty + i * 8;
    int n = n0 + tx;
    t[ty + i * 8][tx] = (n < N) ? src[(size_t)k * N + n] : 0.0f;
  }
  __syncthreads();
#pragma unroll
  for (int i = 0; i < 4; i++) {
    int n = n0 + ty + i * 8;
    int k = k0 + tx;
    if (n < Npad) dst[(size_t)n * K + k] = (bf16_t)t[tx][ty + i * 8];
  }
}

// ======== 8-phase GEMM: C = A(MxK) * Bt(NxK)^T, BM=256 BN=128 BK=64, 8 waves ========
// MODE 0: Of = Ob = acc + bias
// MODE 1: Ob = bf16(Uin + 0.1*tanh(acc + bias))
// MODE 2: Of = Uin + 0.1*tanh(acc + bias), + Ob  (Of aliases Uin; two-pass epilogue)
template <int MODE>
__launch_bounds__(512, 2)
__global__ void k_gemm8(const bf16_t* __restrict__ A, const bf16_t* __restrict__ Bt,
                        const float* __restrict__ bias, const float* Uin,
                        float* Of, bf16_t* __restrict__ Ob,
                        int M, int N, int K) {
  __shared__ bf16_t As[2][256 * 64];  // 64 KiB
  __shared__ bf16_t Bs[2][128 * 64];  // 32 KiB

  const int tid = threadIdx.x;
  const int lane = tid & 63;
  const int wid = tid >> 6;
  const int wm = wid >> 2;  // 0..1  (M half, 128 rows)
  const int wn = wid & 3;   // 0..3  (N quarter, 32 cols)

  // XCD-aware bijective swizzle (grid % 8 == 0 here)
  const int nbx = N >> 7;  // N/128
  int bid = (int)blockIdx.x;
  const int cpx = (int)gridDim.x >> 3;
  bid = (bid & 7) * cpx + (bid >> 3);
  const int bn0 = (bid % nbx) * 128;
  const int bm0 = (bid / nbx) * 256;

  // staging: chunk = 1024B = 8 rows x 128B. lane l -> row l>>3, slot l&7 (16B units).
  // XOR swizzle via pre-swizzled GLOBAL source; LDS stays linear (rule #21).
  const int srow = lane >> 3;
  const int sslotg = (lane & 7) ^ srow;
  const size_t aBase = (size_t)(bm0 + wid * 32 + srow) * K + (size_t)sslotg * 8;
  const size_t bBase = (size_t)(bn0 + wid * 16 + srow) * K + (size_t)sslotg * 8;

  const int frow = lane & 15;
  const int fk = lane >> 4;

  f32x4 acc[8][2];
#pragma unroll
  for (int m = 0; m < 8; m++)
#pragma unroll
    for (int n = 0; n < 2; n++) acc[m][n] = (f32x4){0.f, 0.f, 0.f, 0.f};

  auto stageA = [&](int buf, int kt, int i) {
    gld_lds16(A + aBase + (size_t)i * 8 * K + kt, (char*)&As[buf][0] + (wid * 4 + i) * 1024);
  };
  auto stageB = [&](int buf, int kt, int i) {
    gld_lds16(Bt + bBase + (size_t)i * 8 * K + kt, (char*)&Bs[buf][0] + (wid * 2 + i) * 1024);
  };

  // prologue: stage tile 0 into buf 0 (6 loads in flight)
  stageA(0, 0, 0); stageA(0, 0, 1); stageA(0, 0, 2); stageA(0, 0, 3);
  stageB(0, 0, 0); stageB(0, 0, 1);

  const int NT = K >> 6;
  const int sw = (frow & 7);

  for (int t = 0; t < NT; ++t) {
    const int cur = t & 1;
    if (t + 1 < NT) {
      const int kt1 = (t + 1) << 6;
      stageA(cur ^ 1, kt1, 0); stageA(cur ^ 1, kt1, 1);
      stageA(cur ^ 1, kt1, 2); stageA(cur ^ 1, kt1, 3);
      stageB(cur ^ 1, kt1, 0); stageB(cur ^ 1, kt1, 1);
      asm volatile("s_waitcnt vmcnt(6)" ::: "memory");  // tile t done; t+1 stays in flight
    } else {
      asm volatile("s_waitcnt vmcnt(0)" ::: "memory");
    }
    __builtin_amdgcn_s_barrier();

    const char* pa = (const char*)&As[cur][0] + (wm * 128 + frow) * 128;
    const char* pb = (const char*)&Bs[cur][0] + (wn * 32 + frow) * 128;
    const int sl0 = ((0 + fk) ^ sw) * 16;
    const int sl1 = ((4 + fk) ^ sw) * 16;

    bfrag af[4], bq[2], bq1[2];
    // ---- phase 0: s=0, m=0..3 ----
#pragma unroll
    for (int m = 0; m < 4; m++) af[m] = *reinterpret_cast<const bfrag*>(pa + m * 2048 + sl0);
    bq[0] = *reinterpret_cast<const bfrag*>(pb + sl0);
    bq[1] = *reinterpret_cast<const bfrag*>(pb + 2048 + sl0);
    __builtin_amdgcn_s_barrier();
    __builtin_amdgcn_s_setprio(1);
#pragma unroll
    for (int m = 0; m < 4; m++)
#pragma unroll
      for (int n = 0; n < 2; n++)
        acc[m][n] = __builtin_amdgcn_mfma_f32_16x16x32_bf16(af[m], bq[n], acc[m][n], 0, 0, 0);
    __builtin_amdgcn_s_setprio(0);
    __builtin_amdgcn_s_barrier();

    // ---- phase 1: s=0, m=4..7 ----
#pragma unroll
    for (int m = 0; m < 4; m++) af[m] = *reinterpret_cast<const bfrag*>(pa + (m + 4) * 2048 + sl0);
    __builtin_amdgcn_s_barrier();
    __builtin_amdgcn_s_setprio(1);
#pragma unroll
    for (int m = 0; m < 4; m++)
#pragma unroll
      for (int n = 0; n < 2; n++)
        acc[m + 4][n] = __builtin_amdgcn_mfma_f32_16x16x32_bf16(af[m], bq[n], acc[m + 4][n], 0, 0, 0);
    __builtin_amdgcn_s_setprio(0);
    __builtin_amdgcn_s_barrier();

    // ---- phase 2: s=1, m=0..3 ----
#pragma unroll
    for (int m = 0; m < 4; m++) af[m] = *reinterpret_cast<const bfrag*>(pa + m * 2048 + sl1);
    bq1[0] = *reinterpret_cast<const bfrag*>(pb + sl1);
    bq1[1] = *reinterpret_cast<const bfrag*>(pb + 2048 + sl1);
    __builtin_amdgcn_s_barrier();
    __builtin_amdgcn_s_setprio(1);
#pragma unroll
    for (int m = 0; m < 4; m++)
#pragma unroll
      for (int n = 0; n < 2; n++)
        acc[m][n] = __builtin_amdgcn_mfma_f32_16x16x32_bf16(af[m], bq1[n], acc[m][n], 0, 0, 0);
    __builtin_amdgcn_s_setprio(0);
    __builtin_amdgcn_s_barrier();

    // ---- phase 3: s=1, m=4..7 ----
#pragma unroll
    for (int m = 0; m < 4; m++) af[m] = *reinterpret_cast<const bfrag*>(pa + (m + 4) * 2048 + sl1);
    __builtin_amdgcn_s_barrier();
    __builtin_amdgcn_s_setprio(1);
#pragma unroll
    for (int m = 0; m < 4; m++)
#pragma unroll
      for (int n = 0; n < 2; n++)
        acc[m + 4][n] = __builtin_amdgcn_mfma_f32_16x16x32_bf16(af[m], bq1[n], acc[m + 4][n], 0, 0, 0);
    __builtin_amdgcn_s_setprio(0);
    __builtin_amdgcn_s_barrier();  // also protects buf[cur] before tile t+2 stores
  }

  // epilogue: C/D layout col = lane&15 (-> gn), row = (lane>>4)*4 + j (-> gm)
  if (MODE == 2) {
    // two-pass: batch all Uin loads first (Of aliases Uin; interleaved stores would
    // serialize each load behind the previous store at HBM latency)
    float uv[8][2][4];
#pragma unroll
    for (int m = 0; m < 8; m++)
#pragma unroll
      for (int n = 0; n < 2; n++) {
        const int gn = bn0 + wn * 32 + n * 16 + frow;
#pragma unroll
        for (int j = 0; j < 4; j++) {
          const int gm = bm0 + wm * 128 + m * 16 + fk * 4 + j;
          uv[m][n][j] = Uin[(size_t)gm * N + gn];
        }
      }
#pragma unroll
    for (int m = 0; m < 8; m++)
#pragma unroll
      for (int n = 0; n < 2; n++) {
        const int gn = bn0 + wn * 32 + n * 16 + frow;
#pragma unroll
        for (int j = 0; j < 4; j++) {
          const int gm = bm0 + wm * 128 + m * 16 + fk * 4 + j;
          const size_t off = (size_t)gm * N + gn;
          float v = uv[m][n][j] + 0.1f * tanhf(acc[m][n][j] + bias[gn]);
          Of[off] = v;
          Ob[off] = (bf16_t)v;
        }
      }
  } else {
#pragma unroll
    for (int m = 0; m < 8; m++) {
#pragma unroll
      for (int n = 0; n < 2; n++) {
        const int gn = bn0 + wn * 32 + n * 16 + frow;
#pragma unroll
        for (int j = 0; j < 4; j++) {
          const int gm = bm0 + wm * 128 + m * 16 + fk * 4 + j;
          const size_t off = (size_t)gm * N + gn;
          float v = acc[m][n][j];
          if (MODE == 0) {
            v += bias[gn];
            Of[off] = v;
            Ob[off] = (bf16_t)v;
          } else {  // MODE 1
            v = Uin[off] + 0.1f * tanhf(v + bias[gn]);
            Ob[off] = (bf16_t)v;
          }
        }
      }
    }
  }
}

// ---------------- 128^2 4-wave GEMM - kept for the N=1024 logits GEMM ----------------
// MODE 3: Of = acc + bias, only cols < Nvalid
template <int MODE>
__launch_bounds__(256, 2)
__global__ void k_gemm(const bf16_t* __restrict__ A, const bf16_t* __restrict__ Bt,
                       const float* __restrict__ bias, const float* Uin,
                       float* Of, bf16_t* __restrict__ Ob,
                       int M, int N, int K, int Nvalid) {
  __shared__ bf16_t As2[128 * 64];
  __shared__ bf16_t Bs2[128 * 64];

  const int tid = threadIdx.x;
  const int lane = tid & 63;
  const int wid = tid >> 6;
  const int bn0 = blockIdx.x * 128;
  const int bm0 = blockIdx.y * 128;

  const int srow = lane >> 3;
  const int sslot = (lane & 7) ^ srow;
  const int frow = lane & 15;
  const int fk = lane >> 4;

  f32x4 acc[4][4];
#pragma unroll
  for (int m = 0; m < 4; m++)
#pragma unroll
    for (int n = 0; n < 4; n++) acc[m][n] = (f32x4){0.f, 0.f, 0.f, 0.f};

  const int wm = wid >> 1;
  const int wn = wid & 1;

  const size_t aRowBase = (size_t)(bm0 + wid * 32 + srow) * K + (size_t)sslot * 8;
  const size_t bRowBase = (size_t)(bn0 + wid * 32 + srow) * K + (size_t)sslot * 8;

  for (int kt = 0; kt < K; kt += 64) {
#pragma unroll
    for (int i = 0; i < 4; i++) {
      gld_lds16(A + aRowBase + (size_t)i * 8 * K + kt, (char*)As2 + (wid * 4 + i) * 1024);
      gld_lds16(Bt + bRowBase + (size_t)i * 8 * K + kt, (char*)Bs2 + (wid * 4 + i) * 1024);
    }
    __syncthreads();

#pragma unroll
    for (int s = 0; s < 2; s++) {
      bfrag af[4], bq[4];
#pragma unroll
      for (int m = 0; m < 4; m++) {
        int row = wm * 64 + m * 16 + frow;
        int slot = (s * 4 + fk) ^ (row & 7);
        af[m] = *reinterpret_cast<const bfrag*>((const char*)As2 + row * 128 + slot * 16);
      }
#pragma unroll
      for (int n = 0; n < 4; n++) {
        int row = wn * 64 + n * 16 + frow;
        int slot = (s * 4 + fk) ^ (row & 7);
        bq[n] = *reinterpret_cast<const bfrag*>((const char*)Bs2 + row * 128 + slot * 16);
      }
#pragma unroll
      for (int m = 0; m < 4; m++)
#pragma unroll
        for (int n = 0; n < 4; n++)
          acc[m][n] = __builtin_amdgcn_mfma_f32_16x16x32_bf16(af[m], bq[n], acc[m][n], 0, 0, 0);
    }
    __syncthreads();
  }

#pragma unroll
  for (int m = 0; m < 4; m++) {
#pragma unroll
    for (int n = 0; n < 4; n++) {
      const int gn = bn0 + wn * 64 + n * 16 + frow;
#pragma unroll
      for (int j = 0; j < 4; j++) {
        const int gm = bm0 + wm * 64 + m * 16 + fk * 4 + j;
        const size_t off = (size_t)gm * N + gn;
        float v = acc[m][n][j];
        if (gn < Nvalid) Of[off] = v + bias[gn];
      }
    }
  }
}

// ---------------- row softmax ----------------
__global__ void k_softmax(const float* __restrict__ logits, float* __restrict__ out) {
  __shared__ float red[256];
  const int r = blockIdx.x;
  const float* L = logits + (size_t)r * NPAD_OUT;
  float* O = out + (size_t)r * OUT_DIM;
  const int tid = threadIdx.x;

  float lmax = -INFINITY;
  for (int j = tid; j < OUT_DIM; j += 256) lmax = fmaxf(lmax, L[j]);
  red[tid] = lmax;
  __syncthreads();
  for (int s = 128; s > 0; s >>= 1) {
    if (tid < s) red[tid] = fmaxf(red[tid], red[tid + s]);
    __syncthreads();
  }
  const float rmax = red[0];
  __syncthreads();
  float lsum = 0.f;
  for (int j = tid; j < OUT_DIM; j += 256) {
    float e = expf(L[j] - rmax);
    O[j] = e;
    lsum += e;
  }
  red[tid] = lsum;
  __syncthreads();
  for (int s = 128; s > 0; s >>= 1) {
    if (tid < s) red[tid] += red[tid + s];
    __syncthreads();
  }
  const float inv = 1.0f / red[0];
  for (int j = tid; j < OUT_DIM; j += 256) O[j] *= inv;
}

extern "C" void kernel_launch(void* const* d_in, const int* in_sizes, int n_in,
                              void* d_out, int out_size, void* d_ws, size_t ws_size,
                              hipStream_t stream) {
  const float* x = (const float*)d_in[0];
  const float* W_in = (const float*)d_in[1];
  const float* b_in = (const float*)d_in[2];
  const float* W_out = (const float*)d_in[3];
  const float* b_out = (const float*)d_in[4];
  const float* W[4] = {(const float*)d_in[5], (const float*)d_in[7],
                       (const float*)d_in[9], (const float*)d_in[11]};
  const float* bb[4] = {(const float*)d_in[6], (const float*)d_in[8],
                        (const float*)d_in[10], (const float*)d_in[12]};
  float* out = (float*)d_out;

  // ---- workspace: 72 MiB (proven-safe footprint) ----
  char* ws = (char*)d_ws;
  size_t off = 0;
  auto alloc = [&](size_t bytes) {
    void* p = ws + off;
    off += (bytes + 255) & ~(size_t)255;
    return p;
  };
  float* u = (float*)alloc((size_t)BATCH * UNITS * 4);
  bf16_t* zb[2];
  zb[0] = (bf16_t*)alloc((size_t)BATCH * UNITS * 2);
  zb[1] = (bf16_t*)alloc((size_t)BATCH * UNITS * 2);
  bf16_t* wt = (bf16_t*)alloc((size_t)UNITS * UNITS * 2);
  bf16_t* xb = (bf16_t*)zb[1];  // alias: dead before first block iteration writes zb[1]
  float* logits = u;            // alias: u dead after block 4

  dim3 tb(32, 8);
  const int g8 = (UNITS / 128) * (BATCH / 256);  // 256 blocks

  // z0 = x @ W_in + b_in  -> u (f32), zb[0] (bf16)
  k_f32_to_bf16<<<(BATCH * IN_DIM) / 256, 256, 0, stream>>>(x, xb, BATCH * IN_DIM);
  k_transpose_bf16<<<dim3(UNITS / 32, IN_DIM / 32), tb, 0, stream>>>(W_in, wt, IN_DIM, UNITS, UNITS);
  k_gemm8<0><<<g8, 512, 0, stream>>>(xb, wt, b_in, nullptr, u, zb[0], BATCH, UNITS, IN_DIM);

  // 4 blocks x NITER: y <- u + 0.1*tanh(y @ W_b + b_b)
  int cur = 0;
  for (int b = 0; b < 4; b++) {
    k_transpose_bf16<<<dim3(UNITS / 32, UNITS / 32), tb, 0, stream>>>(W[b], wt, UNITS, UNITS, UNITS);
    for (int t = 0; t < NITER; t++) {
      if (t == NITER - 1 && b < 3)
        k_gemm8<2><<<g8, 512, 0, stream>>>(zb[cur], wt, bb[b], u, u, zb[cur ^ 1],
                                           BATCH, UNITS, UNITS);
      else
        k_gemm8<1><<<g8, 512, 0, stream>>>(zb[cur], wt, bb[b], u, nullptr, zb[cur ^ 1],
                                           BATCH, UNITS, UNITS);
      cur ^= 1;
    }
  }

  // logits + softmax
  k_transpose_bf16<<<dim3(NPAD_OUT / 32, UNITS / 32), tb, 0, stream>>>(W_out, wt, UNITS, OUT_DIM, NPAD_OUT);
  k_gemm<3><<<dim3(NPAD_OUT / 128, BATCH / 128), 256, 0, stream>>>(
      zb[cur], wt, b_out, nullptr, logits, nullptr, BATCH, NPAD_OUT, UNITS, OUT_DIM);
  k_softmax<<<BATCH, 256, 0, stream>>>(logits, out);
}

// Round 5
// 902.836 us; speedup vs baseline: 2.1563x; 1.2657x over previous
//
#include <hip/hip_runtime.h>
#include <math.h>

#define BATCH 4096
#define IN_DIM 1024
#define UNITS 2048
#define OUT_DIM 1000
#define NPAD_OUT 1024
#define NITER 3

typedef __bf16 bf16_t;
typedef __attribute__((ext_vector_type(8))) __bf16 bfrag;
typedef __attribute__((ext_vector_type(4))) float f32x4;

typedef __attribute__((address_space(1))) void gvoid_t;
typedef __attribute__((address_space(3))) void lvoid_t;

__device__ __forceinline__ void gld_lds16(const void* g, void* l) {
  __builtin_amdgcn_global_load_lds((gvoid_t*)g, (lvoid_t*)l, 16, 0, 0);
}

// ---------------- elementwise f32 -> bf16 ----------------
__global__ void k_f32_to_bf16(const float* __restrict__ in, bf16_t* __restrict__ out, int n) {
  int i = blockIdx.x * 256 + threadIdx.x;
  if (i < n) out[i] = (bf16_t)in[i];
}

// ---- transpose f32 (K x N, row stride N) -> bf16 (Npad x K); pads with 0 ----
__global__ void k_transpose_bf16(const float* __restrict__ src, bf16_t* __restrict__ dst,
                                 int K, int N, int Npad) {
  __shared__ float t[32][33];
  int n0 = blockIdx.x * 32;
  int k0 = blockIdx.y * 32;
  int tx = threadIdx.x, ty = threadIdx.y;  // 32 x 8
#pragma unroll
  for (int i = 0; i < 4; i++) {
    int k = k0 + ty + i * 8;
    int n = n0 + tx;
    t[ty + i * 8][tx] = (n < N) ? src[(size_t)k * N + n] : 0.0f;
  }
  __syncthreads();
#pragma unroll
  for (int i = 0; i < 4; i++) {
    int n = n0 + ty + i * 8;
    int k = k0 + tx;
    if (n < Npad) dst[(size_t)n * K + k] = (bf16_t)t[tx][ty + i * 8];
  }
}

// ======== 8-phase GEMM: C = A(MxK) * Bt(NxK)^T, BM=256 BN=128 BK=64, 8 waves ========
// MODE 0: Of = Ob = acc + bias
// MODE 1: Ob = bf16(Uin + 0.1*tanh(acc + bias))
// MODE 2: Of  = Uin + 0.1*tanh(acc + bias), + Ob   (Of ALIASES Uin; in-place fallback)
// MODE 4: Of2 = Uin + 0.1*tanh(acc + bias), + Ob   (Of2 distinct restrict; ping-pong u)
template <int MODE>
__launch_bounds__(512, 2)
__global__ void k_gemm8(const bf16_t* __restrict__ A, const bf16_t* __restrict__ Bt,
                        const float* __restrict__ bias, const float* Uin,
                        float* Of, float* __restrict__ Of2, bf16_t* __restrict__ Ob,
                        int M, int N, int K) {
  __shared__ bf16_t As[2][256 * 64];  // 64 KiB
  __shared__ bf16_t Bs[2][128 * 64];  // 32 KiB

  const int tid = threadIdx.x;
  const int lane = tid & 63;
  const int wid = tid >> 6;
  const int wm = wid >> 2;  // 0..1  (M half, 128 rows)
  const int wn = wid & 3;   // 0..3  (N quarter, 32 cols)

  // XCD-aware bijective swizzle (grid % 8 == 0 here)
  const int nbx = N >> 7;  // N/128
  int bid = (int)blockIdx.x;
  const int cpx = (int)gridDim.x >> 3;
  bid = (bid & 7) * cpx + (bid >> 3);
  const int bn0 = (bid % nbx) * 128;
  const int bm0 = (bid / nbx) * 256;

  // staging: chunk = 1024B = 8 rows x 128B. lane l -> row l>>3, slot l&7 (16B units).
  // XOR swizzle via pre-swizzled GLOBAL source; LDS stays linear (rule #21).
  const int srow = lane >> 3;
  const int sslotg = (lane & 7) ^ srow;
  const size_t aBase = (size_t)(bm0 + wid * 32 + srow) * K + (size_t)sslotg * 8;
  const size_t bBase = (size_t)(bn0 + wid * 16 + srow) * K + (size_t)sslotg * 8;

  const int frow = lane & 15;
  const int fk = lane >> 4;

  f32x4 acc[8][2];
#pragma unroll
  for (int m = 0; m < 8; m++)
#pragma unroll
    for (int n = 0; n < 2; n++) acc[m][n] = (f32x4){0.f, 0.f, 0.f, 0.f};

  auto stageA = [&](int buf, int kt, int i) {
    gld_lds16(A + aBase + (size_t)i * 8 * K + kt, (char*)&As[buf][0] + (wid * 4 + i) * 1024);
  };
  auto stageB = [&](int buf, int kt, int i) {
    gld_lds16(Bt + bBase + (size_t)i * 8 * K + kt, (char*)&Bs[buf][0] + (wid * 2 + i) * 1024);
  };

  // prologue: stage tile 0 into buf 0 (6 loads in flight)
  stageA(0, 0, 0); stageA(0, 0, 1); stageA(0, 0, 2); stageA(0, 0, 3);
  stageB(0, 0, 0); stageB(0, 0, 1);

  const int NT = K >> 6;
  const int sw = (frow & 7);

  for (int t = 0; t < NT; ++t) {
    const int cur = t & 1;
    if (t + 1 < NT) {
      const int kt1 = (t + 1) << 6;
      stageA(cur ^ 1, kt1, 0); stageA(cur ^ 1, kt1, 1);
      stageA(cur ^ 1, kt1, 2); stageA(cur ^ 1, kt1, 3);
      stageB(cur ^ 1, kt1, 0); stageB(cur ^ 1, kt1, 1);
      asm volatile("s_waitcnt vmcnt(6)" ::: "memory");  // tile t done; t+1 stays in flight
    } else {
      asm volatile("s_waitcnt vmcnt(0)" ::: "memory");
    }
    __builtin_amdgcn_s_barrier();

    const char* pa = (const char*)&As[cur][0] + (wm * 128 + frow) * 128;
    const char* pb = (const char*)&Bs[cur][0] + (wn * 32 + frow) * 128;
    const int sl0 = ((0 + fk) ^ sw) * 16;
    const int sl1 = ((4 + fk) ^ sw) * 16;

    bfrag af[4], bq[2], bq1[2];
    // ---- phase 0: s=0, m=0..3 ----
#pragma unroll
    for (int m = 0; m < 4; m++) af[m] = *reinterpret_cast<const bfrag*>(pa + m * 2048 + sl0);
    bq[0] = *reinterpret_cast<const bfrag*>(pb + sl0);
    bq[1] = *reinterpret_cast<const bfrag*>(pb + 2048 + sl0);
    __builtin_amdgcn_s_barrier();
    __builtin_amdgcn_s_setprio(1);
#pragma unroll
    for (int m = 0; m < 4; m++)
#pragma unroll
      for (int n = 0; n < 2; n++)
        acc[m][n] = __builtin_amdgcn_mfma_f32_16x16x32_bf16(af[m], bq[n], acc[m][n], 0, 0, 0);
    __builtin_amdgcn_s_setprio(0);
    __builtin_amdgcn_s_barrier();

    // ---- phase 1: s=0, m=4..7 ----
#pragma unroll
    for (int m = 0; m < 4; m++) af[m] = *reinterpret_cast<const bfrag*>(pa + (m + 4) * 2048 + sl0);
    __builtin_amdgcn_s_barrier();
    __builtin_amdgcn_s_setprio(1);
#pragma unroll
    for (int m = 0; m < 4; m++)
#pragma unroll
      for (int n = 0; n < 2; n++)
        acc[m + 4][n] = __builtin_amdgcn_mfma_f32_16x16x32_bf16(af[m], bq[n], acc[m + 4][n], 0, 0, 0);
    __builtin_amdgcn_s_setprio(0);
    __builtin_amdgcn_s_barrier();

    // ---- phase 2: s=1, m=0..3 ----
#pragma unroll
    for (int m = 0; m < 4; m++) af[m] = *reinterpret_cast<const bfrag*>(pa + m * 2048 + sl1);
    bq1[0] = *reinterpret_cast<const bfrag*>(pb + sl1);
    bq1[1] = *reinterpret_cast<const bfrag*>(pb + 2048 + sl1);
    __builtin_amdgcn_s_barrier();
    __builtin_amdgcn_s_setprio(1);
#pragma unroll
    for (int m = 0; m < 4; m++)
#pragma unroll
      for (int n = 0; n < 2; n++)
        acc[m][n] = __builtin_amdgcn_mfma_f32_16x16x32_bf16(af[m], bq1[n], acc[m][n], 0, 0, 0);
    __builtin_amdgcn_s_setprio(0);
    __builtin_amdgcn_s_barrier();

    // ---- phase 3: s=1, m=4..7 ----
#pragma unroll
    for (int m = 0; m < 4; m++) af[m] = *reinterpret_cast<const bfrag*>(pa + (m + 4) * 2048 + sl1);
    __builtin_amdgcn_s_barrier();
    __builtin_amdgcn_s_setprio(1);
#pragma unroll
    for (int m = 0; m < 4; m++)
#pragma unroll
      for (int n = 0; n < 2; n++)
        acc[m + 4][n] = __builtin_amdgcn_mfma_f32_16x16x32_bf16(af[m], bq1[n], acc[m + 4][n], 0, 0, 0);
    __builtin_amdgcn_s_setprio(0);
    __builtin_amdgcn_s_barrier();  // also protects buf[cur] before tile t+2 stores
  }

  // epilogue: C/D layout col = lane&15 (-> gn), row = (lane>>4)*4 + j (-> gm)
#pragma unroll
  for (int m = 0; m < 8; m++) {
#pragma unroll
    for (int n = 0; n < 2; n++) {
      const int gn = bn0 + wn * 32 + n * 16 + frow;
#pragma unroll
      for (int j = 0; j < 4; j++) {
        const int gm = bm0 + wm * 128 + m * 16 + fk * 4 + j;
        const size_t off = (size_t)gm * N + gn;
        float v = acc[m][n][j];
        if (MODE == 0) {
          v += bias[gn];
          Of[off] = v;
          Ob[off] = (bf16_t)v;
        } else if (MODE == 1) {
          v = Uin[off] + 0.1f * tanhf(v + bias[gn]);
          Ob[off] = (bf16_t)v;
        } else if (MODE == 2) {
          v = Uin[off] + 0.1f * tanhf(v + bias[gn]);
          Of[off] = v;
          Ob[off] = (bf16_t)v;
        } else {  // MODE 4: distinct restrict output
          v = Uin[off] + 0.1f * tanhf(v + bias[gn]);
          Of2[off] = v;
          Ob[off] = (bf16_t)v;
        }
      }
    }
  }
}

// ---------------- 128^2 4-wave GEMM - kept for the N=1024 logits GEMM ----------------
__launch_bounds__(256, 2)
__global__ void k_gemm_log(const bf16_t* __restrict__ A, const bf16_t* __restrict__ Bt,
                           const float* __restrict__ bias,
                           float* __restrict__ Of,
                           int M, int N, int K, int Nvalid) {
  __shared__ bf16_t As2[128 * 64];
  __shared__ bf16_t Bs2[128 * 64];

  const int tid = threadIdx.x;
  const int lane = tid & 63;
  const int wid = tid >> 6;
  const int bn0 = blockIdx.x * 128;
  const int bm0 = blockIdx.y * 128;

  const int srow = lane >> 3;
  const int sslot = (lane & 7) ^ srow;
  const int frow = lane & 15;
  const int fk = lane >> 4;

  f32x4 acc[4][4];
#pragma unroll
  for (int m = 0; m < 4; m++)
#pragma unroll
    for (int n = 0; n < 4; n++) acc[m][n] = (f32x4){0.f, 0.f, 0.f, 0.f};

  const int wm = wid >> 1;
  const int wn = wid & 1;

  const size_t aRowBase = (size_t)(bm0 + wid * 32 + srow) * K + (size_t)sslot * 8;
  const size_t bRowBase = (size_t)(bn0 + wid * 32 + srow) * K + (size_t)sslot * 8;

  for (int kt = 0; kt < K; kt += 64) {
#pragma unroll
    for (int i = 0; i < 4; i++) {
      gld_lds16(A + aRowBase + (size_t)i * 8 * K + kt, (char*)As2 + (wid * 4 + i) * 1024);
      gld_lds16(Bt + bRowBase + (size_t)i * 8 * K + kt, (char*)Bs2 + (wid * 4 + i) * 1024);
    }
    __syncthreads();

#pragma unroll
    for (int s = 0; s < 2; s++) {
      bfrag af[4], bq[4];
#pragma unroll
      for (int m = 0; m < 4; m++) {
        int row = wm * 64 + m * 16 + frow;
        int slot = (s * 4 + fk) ^ (row & 7);
        af[m] = *reinterpret_cast<const bfrag*>((const char*)As2 + row * 128 + slot * 16);
      }
#pragma unroll
      for (int n = 0; n < 4; n++) {
        int row = wn * 64 + n * 16 + frow;
        int slot = (s * 4 + fk) ^ (row & 7);
        bq[n] = *reinterpret_cast<const bfrag*>((const char*)Bs2 + row * 128 + slot * 16);
      }
#pragma unroll
      for (int m = 0; m < 4; m++)
#pragma unroll
        for (int n = 0; n < 4; n++)
          acc[m][n] = __builtin_amdgcn_mfma_f32_16x16x32_bf16(af[m], bq[n], acc[m][n], 0, 0, 0);
    }
    __syncthreads();
  }

#pragma unroll
  for (int m = 0; m < 4; m++) {
#pragma unroll
    for (int n = 0; n < 4; n++) {
      const int gn = bn0 + wn * 64 + n * 16 + frow;
#pragma unroll
      for (int j = 0; j < 4; j++) {
        const int gm = bm0 + wm * 64 + m * 16 + fk * 4 + j;
        const size_t off = (size_t)gm * N + gn;
        if (gn < Nvalid) Of[off] = acc[m][n][j] + bias[gn];
      }
    }
  }
}

// ---------------- row softmax ----------------
__global__ void k_softmax(const float* __restrict__ logits, float* __restrict__ out) {
  __shared__ float red[256];
  const int r = blockIdx.x;
  const float* L = logits + (size_t)r * NPAD_OUT;
  float* O = out + (size_t)r * OUT_DIM;
  const int tid = threadIdx.x;

  float lmax = -INFINITY;
  for (int j = tid; j < OUT_DIM; j += 256) lmax = fmaxf(lmax, L[j]);
  red[tid] = lmax;
  __syncthreads();
  for (int s = 128; s > 0; s >>= 1) {
    if (tid < s) red[tid] = fmaxf(red[tid], red[tid + s]);
    __syncthreads();
  }
  const float rmax = red[0];
  __syncthreads();
  float lsum = 0.f;
  for (int j = tid; j < OUT_DIM; j += 256) {
    float e = expf(L[j] - rmax);
    O[j] = e;
    lsum += e;
  }
  red[tid] = lsum;
  __syncthreads();
  for (int s = 128; s > 0; s >>= 1) {
    if (tid < s) red[tid] += red[tid + s];
    __syncthreads();
  }
  const float inv = 1.0f / red[0];
  for (int j = tid; j < OUT_DIM; j += 256) O[j] *= inv;
}

extern "C" void kernel_launch(void* const* d_in, const int* in_sizes, int n_in,
                              void* d_out, int out_size, void* d_ws, size_t ws_size,
                              hipStream_t stream) {
  const float* x = (const float*)d_in[0];
  const float* W_in = (const float*)d_in[1];
  const float* b_in = (const float*)d_in[2];
  const float* W_out = (const float*)d_in[3];
  const float* b_out = (const float*)d_in[4];
  const float* W[4] = {(const float*)d_in[5], (const float*)d_in[7],
                       (const float*)d_in[9], (const float*)d_in[11]};
  const float* bb[4] = {(const float*)d_in[6], (const float*)d_in[8],
                        (const float*)d_in[10], (const float*)d_in[12]};
  float* out = (float*)d_out;

  // ---- workspace: base layout 72 MiB (proven); optional +32 MiB u ping-pong ----
  char* ws = (char*)d_ws;
  size_t off = 0;
  auto alloc = [&](size_t bytes) {
    void* p = ws + off;
    off += (bytes + 255) & ~(size_t)255;
    return p;
  };
  float* u = (float*)alloc((size_t)BATCH * UNITS * 4);     // u0
  bf16_t* zb[2];
  zb[0] = (bf16_t*)alloc((size_t)BATCH * UNITS * 2);
  zb[1] = (bf16_t*)alloc((size_t)BATCH * UNITS * 2);
  bf16_t* wt = (bf16_t*)alloc((size_t)UNITS * UNITS * 2);
  size_t base_end = off;
  float* u1 = (float*)alloc((size_t)BATCH * UNITS * 4);    // optional u1
  const bool pingpong = (ws_size >= off);                  // deterministic per session
  bf16_t* xb = (bf16_t*)zb[1];  // alias: dead before first block iteration writes zb[1]
  float* logits = u;            // alias: u0 dead by logits time in both paths
  (void)base_end;

  dim3 tb(32, 8);
  const int g8 = (UNITS / 128) * (BATCH / 256);  // 256 blocks

  // z0 = x @ W_in + b_in  -> u0 (f32), zb[0] (bf16)
  k_f32_to_bf16<<<(BATCH * IN_DIM) / 256, 256, 0, stream>>>(x, xb, BATCH * IN_DIM);
  k_transpose_bf16<<<dim3(UNITS / 32, IN_DIM / 32), tb, 0, stream>>>(W_in, wt, IN_DIM, UNITS, UNITS);
  k_gemm8<0><<<g8, 512, 0, stream>>>(xb, wt, b_in, nullptr, u, nullptr, zb[0],
                                     BATCH, UNITS, IN_DIM);

  // 4 blocks x NITER: y <- u + 0.1*tanh(y @ W_b + b_b)
  int cur = 0;
  float* ucur = u;   // current block's u_in
  for (int b = 0; b < 4; b++) {
    k_transpose_bf16<<<dim3(UNITS / 32, UNITS / 32), tb, 0, stream>>>(W[b], wt, UNITS, UNITS, UNITS);
    for (int t = 0; t < NITER; t++) {
      if (t == NITER - 1 && b < 3) {
        if (pingpong) {
          float* unext = (ucur == u) ? u1 : u;
          k_gemm8<4><<<g8, 512, 0, stream>>>(zb[cur], wt, bb[b], ucur, nullptr, unext,
                                             zb[cur ^ 1], BATCH, UNITS, UNITS);
          ucur = unext;
        } else {
          k_gemm8<2><<<g8, 512, 0, stream>>>(zb[cur], wt, bb[b], ucur, ucur, nullptr,
                                             zb[cur ^ 1], BATCH, UNITS, UNITS);
        }
      } else {
        k_gemm8<1><<<g8, 512, 0, stream>>>(zb[cur], wt, bb[b], ucur, nullptr, nullptr,
                                           zb[cur ^ 1], BATCH, UNITS, UNITS);
      }
      cur ^= 1;
    }
  }

  // logits + softmax  (logits aliases u0, dead by now in both paths)
  k_transpose_bf16<<<dim3(NPAD_OUT / 32, UNITS / 32), tb, 0, stream>>>(W_out, wt, UNITS, OUT_DIM, NPAD_OUT);
  k_gemm_log<<<dim3(NPAD_OUT / 128, BATCH / 128), 256, 0, stream>>>(
      zb[cur], wt, b_out, logits, BATCH, NPAD_OUT, UNITS, OUT_DIM);
  k_softmax<<<BATCH, 256, 0, stream>>>(logits, out);
}

// Round 6
// 866.009 us; speedup vs baseline: 2.2480x; 1.0425x over previous
//
#include <hip/hip_runtime.h>
#include <math.h>

#define BATCH 4096
#define IN_DIM 1024
#define UNITS 2048
#define OUT_DIM 1000
#define NPAD_OUT 1024
#define NITER 3

typedef __bf16 bf16_t;
typedef __attribute__((ext_vector_type(8))) __bf16 bfrag;
typedef __attribute__((ext_vector_type(4))) float f32x4;

typedef __attribute__((address_space(1))) void gvoid_t;
typedef __attribute__((address_space(3))) void lvoid_t;

__device__ __forceinline__ void gld_lds16(const void* g, void* l) {
  __builtin_amdgcn_global_load_lds((gvoid_t*)g, (lvoid_t*)l, 16, 0, 0);
}

// ---------------- elementwise f32 -> bf16 ----------------
__global__ void k_f32_to_bf16(const float* __restrict__ in, bf16_t* __restrict__ out, int n) {
  int i = blockIdx.x * 256 + threadIdx.x;
  if (i < n) out[i] = (bf16_t)in[i];
}

// ---- transpose f32 (K x N, row stride N) -> bf16 (Npad x K); pads with 0 ----
__global__ void k_transpose_bf16(const float* __restrict__ src, bf16_t* __restrict__ dst,
                                 int K, int N, int Npad) {
  __shared__ float t[32][33];
  int n0 = blockIdx.x * 32;
  int k0 = blockIdx.y * 32;
  int tx = threadIdx.x, ty = threadIdx.y;  // 32 x 8
#pragma unroll
  for (int i = 0; i < 4; i++) {
    int k = k0 + ty + i * 8;
    int n = n0 + tx;
    t[ty + i * 8][tx] = (n < N) ? src[(size_t)k * N + n] : 0.0f;
  }
  __syncthreads();
#pragma unroll
  for (int i = 0; i < 4; i++) {
    int n = n0 + ty + i * 8;
    int k = k0 + tx;
    if (n < Npad) dst[(size_t)n * K + k] = (bf16_t)t[tx][ty + i * 8];
  }
}

// ======== 8-wave GEMM: C = A(MxK) * Bt(NxK)^T, BM=256 BN=128 BK=64, fat 2-phase ========
// MODE 0: Ob = bf16(acc + bias)
// MODE 1: Ob = bf16( (f32)Uin + 0.1*tanh(acc + bias) )   (Uin bf16, all state bf16)
template <int MODE>
__launch_bounds__(512, 2)
__global__ void k_gemm8(const bf16_t* __restrict__ A, const bf16_t* __restrict__ Bt,
                        const float* __restrict__ bias, const bf16_t* __restrict__ Uin,
                        bf16_t* __restrict__ Ob,
                        int M, int N, int K) {
  __shared__ bf16_t As[2][256 * 64];  // 64 KiB
  __shared__ bf16_t Bs[2][128 * 64];  // 32 KiB

  const int tid = threadIdx.x;
  const int lane = tid & 63;
  const int wid = tid >> 6;
  const int wm = wid >> 2;  // 0..1  (M half, 128 rows)
  const int wn = wid & 3;   // 0..3  (N quarter, 32 cols)

  // XCD-aware bijective swizzle (grid % 8 == 0 here)
  const int nbx = N >> 7;  // N/128
  int bid = (int)blockIdx.x;
  const int cpx = (int)gridDim.x >> 3;
  bid = (bid & 7) * cpx + (bid >> 3);
  const int bn0 = (bid % nbx) * 128;
  const int bm0 = (bid / nbx) * 256;

  // staging: chunk = 1024B = 8 rows x 128B. lane l -> row l>>3, slot l&7 (16B units).
  // XOR swizzle via pre-swizzled GLOBAL source; LDS stays linear (rule #21).
  const int srow = lane >> 3;
  const int sslotg = (lane & 7) ^ srow;
  const size_t aBase = (size_t)(bm0 + wid * 32 + srow) * K + (size_t)sslotg * 8;
  const size_t bBase = (size_t)(bn0 + wid * 16 + srow) * K + (size_t)sslotg * 8;

  const int frow = lane & 15;
  const int fk = lane >> 4;

  f32x4 acc[8][2];
#pragma unroll
  for (int m = 0; m < 8; m++)
#pragma unroll
    for (int n = 0; n < 2; n++) acc[m][n] = (f32x4){0.f, 0.f, 0.f, 0.f};

  auto stageA = [&](int buf, int kt, int i) {
    gld_lds16(A + aBase + (size_t)i * 8 * K + kt, (char*)&As[buf][0] + (wid * 4 + i) * 1024);
  };
  auto stageB = [&](int buf, int kt, int i) {
    gld_lds16(Bt + bBase + (size_t)i * 8 * K + kt, (char*)&Bs[buf][0] + (wid * 2 + i) * 1024);
  };

  // prologue: stage tile 0 into buf 0 (6 loads in flight)
  stageA(0, 0, 0); stageA(0, 0, 1); stageA(0, 0, 2); stageA(0, 0, 3);
  stageB(0, 0, 0); stageB(0, 0, 1);

  const int NT = K >> 6;
  const int sw = (frow & 7);

  for (int t = 0; t < NT; ++t) {
    const int cur = t & 1;
    if (t + 1 < NT) {
      const int kt1 = (t + 1) << 6;
      stageA(cur ^ 1, kt1, 0); stageA(cur ^ 1, kt1, 1);
      stageA(cur ^ 1, kt1, 2); stageA(cur ^ 1, kt1, 3);
      stageB(cur ^ 1, kt1, 0); stageB(cur ^ 1, kt1, 1);
      asm volatile("s_waitcnt vmcnt(6)" ::: "memory");  // tile t done; t+1 stays in flight
    } else {
      asm volatile("s_waitcnt vmcnt(0)" ::: "memory");
    }
    __builtin_amdgcn_s_barrier();

    const char* pa = (const char*)&As[cur][0] + (wm * 128 + frow) * 128;
    const char* pb = (const char*)&Bs[cur][0] + (wn * 32 + frow) * 128;
    const int sl0 = ((0 + fk) ^ sw) * 16;
    const int sl1 = ((4 + fk) ^ sw) * 16;

    bfrag af[8], bq[2];
    // ---- fat phase A: s=0, all 8 m-frags + 2 B-frags, 16 MFMA ----
#pragma unroll
    for (int m = 0; m < 8; m++) af[m] = *reinterpret_cast<const bfrag*>(pa + m * 2048 + sl0);
    bq[0] = *reinterpret_cast<const bfrag*>(pb + sl0);
    bq[1] = *reinterpret_cast<const bfrag*>(pb + 2048 + sl0);
    __builtin_amdgcn_s_barrier();
    __builtin_amdgcn_s_setprio(1);
#pragma unroll
    for (int m = 0; m < 8; m++)
#pragma unroll
      for (int n = 0; n < 2; n++)
        acc[m][n] = __builtin_amdgcn_mfma_f32_16x16x32_bf16(af[m], bq[n], acc[m][n], 0, 0, 0);
    __builtin_amdgcn_s_setprio(0);
    __builtin_amdgcn_s_barrier();

    // ---- fat phase B: s=1 ----
#pragma unroll
    for (int m = 0; m < 8; m++) af[m] = *reinterpret_cast<const bfrag*>(pa + m * 2048 + sl1);
    bq[0] = *reinterpret_cast<const bfrag*>(pb + sl1);
    bq[1] = *reinterpret_cast<const bfrag*>(pb + 2048 + sl1);
    __builtin_amdgcn_s_barrier();
    __builtin_amdgcn_s_setprio(1);
#pragma unroll
    for (int m = 0; m < 8; m++)
#pragma unroll
      for (int n = 0; n < 2; n++)
        acc[m][n] = __builtin_amdgcn_mfma_f32_16x16x32_bf16(af[m], bq[n], acc[m][n], 0, 0, 0);
    __builtin_amdgcn_s_setprio(0);
    __builtin_amdgcn_s_barrier();  // also protects buf[cur] before tile t+2 stores
  }

  // epilogue: C/D layout col = lane&15 (-> gn), row = (lane>>4)*4 + j (-> gm)
#pragma unroll
  for (int m = 0; m < 8; m++) {
#pragma unroll
    for (int n = 0; n < 2; n++) {
      const int gn = bn0 + wn * 32 + n * 16 + frow;
#pragma unroll
      for (int j = 0; j < 4; j++) {
        const int gm = bm0 + wm * 128 + m * 16 + fk * 4 + j;
        const size_t off = (size_t)gm * N + gn;
        float v = acc[m][n][j];
        if (MODE == 0) {
          Ob[off] = (bf16_t)(v + bias[gn]);
        } else {  // MODE 1
          v = (float)Uin[off] + 0.1f * tanhf(v + bias[gn]);
          Ob[off] = (bf16_t)v;
        }
      }
    }
  }
}

// ---------------- 128^2 4-wave GEMM - kept for the N=1024 logits GEMM ----------------
__launch_bounds__(256, 2)
__global__ void k_gemm_log(const bf16_t* __restrict__ A, const bf16_t* __restrict__ Bt,
                           const float* __restrict__ bias,
                           float* __restrict__ Of,
                           int M, int N, int K, int Nvalid) {
  __shared__ bf16_t As2[128 * 64];
  __shared__ bf16_t Bs2[128 * 64];

  const int tid = threadIdx.x;
  const int lane = tid & 63;
  const int wid = tid >> 6;
  const int bn0 = blockIdx.x * 128;
  const int bm0 = blockIdx.y * 128;

  const int srow = lane >> 3;
  const int sslot = (lane & 7) ^ srow;
  const int frow = lane & 15;
  const int fk = lane >> 4;

  f32x4 acc[4][4];
#pragma unroll
  for (int m = 0; m < 4; m++)
#pragma unroll
    for (int n = 0; n < 4; n++) acc[m][n] = (f32x4){0.f, 0.f, 0.f, 0.f};

  const int wm = wid >> 1;
  const int wn = wid & 1;

  const size_t aRowBase = (size_t)(bm0 + wid * 32 + srow) * K + (size_t)sslot * 8;
  const size_t bRowBase = (size_t)(bn0 + wid * 32 + srow) * K + (size_t)sslot * 8;

  for (int kt = 0; kt < K; kt += 64) {
#pragma unroll
    for (int i = 0; i < 4; i++) {
      gld_lds16(A + aRowBase + (size_t)i * 8 * K + kt, (char*)As2 + (wid * 4 + i) * 1024);
      gld_lds16(Bt + bRowBase + (size_t)i * 8 * K + kt, (char*)Bs2 + (wid * 4 + i) * 1024);
    }
    __syncthreads();

#pragma unroll
    for (int s = 0; s < 2; s++) {
      bfrag af[4], bq[4];
#pragma unroll
      for (int m = 0; m < 4; m++) {
        int row = wm * 64 + m * 16 + frow;
        int slot = (s * 4 + fk) ^ (row & 7);
        af[m] = *reinterpret_cast<const bfrag*>((const char*)As2 + row * 128 + slot * 16);
      }
#pragma unroll
      for (int n = 0; n < 4; n++) {
        int row = wn * 64 + n * 16 + frow;
        int slot = (s * 4 + fk) ^ (row & 7);
        bq[n] = *reinterpret_cast<const bfrag*>((const char*)Bs2 + row * 128 + slot * 16);
      }
#pragma unroll
      for (int m = 0; m < 4; m++)
#pragma unroll
        for (int n = 0; n < 4; n++)
          acc[m][n] = __builtin_amdgcn_mfma_f32_16x16x32_bf16(af[m], bq[n], acc[m][n], 0, 0, 0);
    }
    __syncthreads();
  }

#pragma unroll
  for (int m = 0; m < 4; m++) {
#pragma unroll
    for (int n = 0; n < 4; n++) {
      const int gn = bn0 + wn * 64 + n * 16 + frow;
#pragma unroll
      for (int j = 0; j < 4; j++) {
        const int gm = bm0 + wm * 64 + m * 16 + fk * 4 + j;
        const size_t off = (size_t)gm * N + gn;
        if (gn < Nvalid) Of[off] = acc[m][n][j] + bias[gn];
      }
    }
  }
}

// ---------------- row softmax ----------------
__global__ void k_softmax(const float* __restrict__ logits, float* __restrict__ out) {
  __shared__ float red[256];
  const int r = blockIdx.x;
  const float* L = logits + (size_t)r * NPAD_OUT;
  float* O = out + (size_t)r * OUT_DIM;
  const int tid = threadIdx.x;

  float lmax = -INFINITY;
  for (int j = tid; j < OUT_DIM; j += 256) lmax = fmaxf(lmax, L[j]);
  red[tid] = lmax;
  __syncthreads();
  for (int s = 128; s > 0; s >>= 1) {
    if (tid < s) red[tid] = fmaxf(red[tid], red[tid + s]);
    __syncthreads();
  }
  const float rmax = red[0];
  __syncthreads();
  float lsum = 0.f;
  for (int j = tid; j < OUT_DIM; j += 256) {
    float e = expf(L[j] - rmax);
    O[j] = e;
    lsum += e;
  }
  red[tid] = lsum;
  __syncthreads();
  for (int s = 128; s > 0; s >>= 1) {
    if (tid < s) red[tid] += red[tid + s];
    __syncthreads();
  }
  const float inv = 1.0f / red[0];
  for (int j = tid; j < OUT_DIM; j += 256) O[j] *= inv;
}

extern "C" void kernel_launch(void* const* d_in, const int* in_sizes, int n_in,
                              void* d_out, int out_size, void* d_ws, size_t ws_size,
                              hipStream_t stream) {
  const float* x = (const float*)d_in[0];
  const float* W_in = (const float*)d_in[1];
  const float* b_in = (const float*)d_in[2];
  const float* W_out = (const float*)d_in[3];
  const float* b_out = (const float*)d_in[4];
  const float* W[4] = {(const float*)d_in[5], (const float*)d_in[7],
                       (const float*)d_in[9], (const float*)d_in[11]};
  const float* bb[4] = {(const float*)d_in[6], (const float*)d_in[8],
                        (const float*)d_in[10], (const float*)d_in[12]};
  float* out = (float*)d_out;

  // ---- workspace: 3x16 + 8 + 16 = 72 MiB (proven-safe footprint) ----
  char* ws = (char*)d_ws;
  size_t off = 0;
  auto alloc = [&](size_t bytes) {
    void* p = ws + off;
    off += (bytes + 255) & ~(size_t)255;
    return p;
  };
  bf16_t* B0 = (bf16_t*)alloc((size_t)BATCH * UNITS * 2);
  bf16_t* B1 = (bf16_t*)alloc((size_t)BATCH * UNITS * 2);
  bf16_t* B2 = (bf16_t*)alloc((size_t)BATCH * UNITS * 2);
  bf16_t* wt = (bf16_t*)alloc((size_t)UNITS * UNITS * 2);
  float* logits = (float*)alloc((size_t)BATCH * NPAD_OUT * 4);
  bf16_t* xb = B1;  // alias: dead before block-0 iter-0 writes B1

  dim3 tb(32, 8);
  const int g8 = (UNITS / 128) * (BATCH / 256);  // 256 blocks

  // z0 = x @ W_in + b_in  -> B0 (bf16); B0 is block 0's residual base u
  k_f32_to_bf16<<<(BATCH * IN_DIM) / 256, 256, 0, stream>>>(x, xb, BATCH * IN_DIM);
  k_transpose_bf16<<<dim3(UNITS / 32, IN_DIM / 32), tb, 0, stream>>>(W_in, wt, IN_DIM, UNITS, UNITS);
  k_gemm8<0><<<g8, 512, 0, stream>>>(xb, wt, b_in, nullptr, B0, BATCH, UNITS, IN_DIM);

  // 4 blocks x NITER: y <- u + 0.1*tanh(y @ W_b + b_b); all state bf16, 3-buffer rotation
  bf16_t* ub = B0;
  for (int b = 0; b < 4; b++) {
    k_transpose_bf16<<<dim3(UNITS / 32, UNITS / 32), tb, 0, stream>>>(W[b], wt, UNITS, UNITS, UNITS);
    bf16_t* others[2];
    int k = 0;
    if (B0 != ub) others[k++] = B0;
    if (B1 != ub) others[k++] = B1;
    if (B2 != ub) others[k++] = B2;
    bf16_t* src = ub;  // y_0 = u
    for (int t = 0; t < NITER; t++) {
      bf16_t* dst = others[t & 1];
      k_gemm8<1><<<g8, 512, 0, stream>>>(src, wt, bb[b], ub, dst, BATCH, UNITS, UNITS);
      src = dst;
    }
    ub = src;  // block output becomes next block's residual base
  }

  // logits + softmax
  k_transpose_bf16<<<dim3(NPAD_OUT / 32, UNITS / 32), tb, 0, stream>>>(W_out, wt, UNITS, OUT_DIM, NPAD_OUT);
  k_gemm_log<<<dim3(NPAD_OUT / 128, BATCH / 128), 256, 0, stream>>>(
      ub, wt, b_out, logits, BATCH, NPAD_OUT, UNITS, OUT_DIM);
  k_softmax<<<BATCH, 256, 0, stream>>>(logits, out);
}

// Round 7
// 775.865 us; speedup vs baseline: 2.5092x; 1.1162x over previous
//
#include <hip/hip_runtime.h>
#include <math.h>

#define BATCH 4096
#define IN_DIM 1024
#define UNITS 2048
#define OUT_DIM 1000
#define NPAD_OUT 1024
#define NITER 3

typedef __bf16 bf16_t;
typedef __attribute__((ext_vector_type(8))) __bf16 bfrag;
typedef __attribute__((ext_vector_type(4))) float f32x4;

typedef __attribute__((address_space(1))) void gvoid_t;
typedef __attribute__((address_space(3))) void lvoid_t;

__device__ __forceinline__ void gld_lds16(const void* g, void* l) {
  __builtin_amdgcn_global_load_lds((gvoid_t*)g, (lvoid_t*)l, 16, 0, 0);
}

// fast tanh: 1 - 2/(exp2(2*log2e*x)+1); v_exp_f32+v_rcp_f32, ~1ulp f32 (bf16-irrelevant)
__device__ __forceinline__ float fast_tanh(float x) {
  float e, r;
  asm("v_exp_f32 %0, %1" : "=v"(e) : "v"(x * 2.88539008177793f));
  asm("v_rcp_f32 %0, %1" : "=v"(r) : "v"(e + 1.0f));
  return __builtin_fmaf(-2.0f, r, 1.0f);
}

// ---------------- elementwise f32 -> bf16 ----------------
__global__ void k_f32_to_bf16(const float* __restrict__ in, bf16_t* __restrict__ out, int n) {
  int i = blockIdx.x * 256 + threadIdx.x;
  if (i < n) out[i] = (bf16_t)in[i];
}

// ---- transpose f32 (K x N, row stride N) -> bf16 (Npad x K); pads with 0 ----
__global__ void k_transpose_bf16(const float* __restrict__ src, bf16_t* __restrict__ dst,
                                 int K, int N, int Npad) {
  __shared__ float t[32][33];
  int n0 = blockIdx.x * 32;
  int k0 = blockIdx.y * 32;
  int tx = threadIdx.x, ty = threadIdx.y;  // 32 x 8
#pragma unroll
  for (int i = 0; i < 4; i++) {
    int k = k0 + ty + i * 8;
    int n = n0 + tx;
    t[ty + i * 8][tx] = (n < N) ? src[(size_t)k * N + n] : 0.0f;
  }
  __syncthreads();
#pragma unroll
  for (int i = 0; i < 4; i++) {
    int n = n0 + ty + i * 8;
    int k = k0 + tx;
    if (n < Npad) dst[(size_t)n * K + k] = (bf16_t)t[tx][ty + i * 8];
  }
}

// ======== 8-wave GEMM: C = A(MxK) * Bt(NxK)^T, BM=256 BN=128 BK=64 ========
// Triple-buffered LDS, 2-K-tiles-ahead prefetch (vmcnt(12) steady state).
// MODE 0: Ob = bf16(acc + bias)
// MODE 1: Ob = bf16( (f32)Uin + 0.1*tanh(acc + bias) )   (all state bf16)
template <int MODE>
__launch_bounds__(512, 2)
__global__ void k_gemm8(const bf16_t* __restrict__ A, const bf16_t* __restrict__ Bt,
                        const float* __restrict__ bias, const bf16_t* __restrict__ Uin,
                        bf16_t* __restrict__ Ob,
                        int M, int N, int K) {
  __shared__ bf16_t As[3][256 * 64];  // 96 KiB
  __shared__ bf16_t Bs[3][128 * 64];  // 48 KiB

  const int tid = threadIdx.x;
  const int lane = tid & 63;
  const int wid = tid >> 6;
  const int wm = wid >> 2;  // 0..1  (M half, 128 rows)
  const int wn = wid & 3;   // 0..3  (N quarter, 32 cols)

  // XCD-aware bijective swizzle (grid % 8 == 0 here)
  const int nbx = N >> 7;  // N/128
  int bid = (int)blockIdx.x;
  const int cpx = (int)gridDim.x >> 3;
  bid = (bid & 7) * cpx + (bid >> 3);
  const int bn0 = (bid % nbx) * 128;
  const int bm0 = (bid / nbx) * 256;

  // staging: chunk = 1024B = 8 rows x 128B. lane l -> row l>>3, slot l&7 (16B units).
  // XOR swizzle via pre-swizzled GLOBAL source; LDS stays linear (rule #21).
  const int srow = lane >> 3;
  const int sslotg = (lane & 7) ^ srow;
  const size_t aBase = (size_t)(bm0 + wid * 32 + srow) * K + (size_t)sslotg * 8;
  const size_t bBase = (size_t)(bn0 + wid * 16 + srow) * K + (size_t)sslotg * 8;

  const int frow = lane & 15;
  const int fk = lane >> 4;

  f32x4 acc[8][2];
#pragma unroll
  for (int m = 0; m < 8; m++)
#pragma unroll
    for (int n = 0; n < 2; n++) acc[m][n] = (f32x4){0.f, 0.f, 0.f, 0.f};

  auto stageA = [&](int buf, int kt, int i) {
    gld_lds16(A + aBase + (size_t)i * 8 * K + kt, (char*)&As[buf][0] + (wid * 4 + i) * 1024);
  };
  auto stageB = [&](int buf, int kt, int i) {
    gld_lds16(Bt + bBase + (size_t)i * 8 * K + kt, (char*)&Bs[buf][0] + (wid * 2 + i) * 1024);
  };
  auto stageTile = [&](int buf, int kt) {
    stageA(buf, kt, 0); stageA(buf, kt, 1); stageA(buf, kt, 2); stageA(buf, kt, 3);
    stageB(buf, kt, 0); stageB(buf, kt, 1);
  };

  const int NT = K >> 6;
  // prologue: tiles 0,1 in flight (12 loads)
  stageTile(0, 0);
  stageTile(1, 64);

  const int sw = (frow & 7);
  int cur = 0;

  for (int t = 0; t < NT; ++t) {
    if (t + 2 < NT) {
      const int nb = (cur + 2 >= 3) ? cur - 1 : cur + 2;
      stageTile(nb, (t + 2) << 6);
      asm volatile("s_waitcnt vmcnt(12)" ::: "memory");  // tile t done; t+1,t+2 in flight
    } else if (t + 1 < NT) {
      asm volatile("s_waitcnt vmcnt(6)" ::: "memory");   // tile t done; t+1 in flight
    } else {
      asm volatile("s_waitcnt vmcnt(0)" ::: "memory");
    }
    __builtin_amdgcn_s_barrier();

    const char* pa = (const char*)&As[cur][0] + (wm * 128 + frow) * 128;
    const char* pb = (const char*)&Bs[cur][0] + (wn * 32 + frow) * 128;
    const int sl0 = ((0 + fk) ^ sw) * 16;
    const int sl1 = ((4 + fk) ^ sw) * 16;

    bfrag af[8], bq[2];
    // ---- fat phase A: s=0, 16 MFMA ----
#pragma unroll
    for (int m = 0; m < 8; m++) af[m] = *reinterpret_cast<const bfrag*>(pa + m * 2048 + sl0);
    bq[0] = *reinterpret_cast<const bfrag*>(pb + sl0);
    bq[1] = *reinterpret_cast<const bfrag*>(pb + 2048 + sl0);
    __builtin_amdgcn_s_barrier();
    __builtin_amdgcn_s_setprio(1);
#pragma unroll
    for (int m = 0; m < 8; m++)
#pragma unroll
      for (int n = 0; n < 2; n++)
        acc[m][n] = __builtin_amdgcn_mfma_f32_16x16x32_bf16(af[m], bq[n], acc[m][n], 0, 0, 0);
    __builtin_amdgcn_s_setprio(0);
    __builtin_amdgcn_s_barrier();

    // ---- fat phase B: s=1, 16 MFMA ----
#pragma unroll
    for (int m = 0; m < 8; m++) af[m] = *reinterpret_cast<const bfrag*>(pa + m * 2048 + sl1);
    bq[0] = *reinterpret_cast<const bfrag*>(pb + sl1);
    bq[1] = *reinterpret_cast<const bfrag*>(pb + 2048 + sl1);
    __builtin_amdgcn_s_barrier();
    __builtin_amdgcn_s_setprio(1);
#pragma unroll
    for (int m = 0; m < 8; m++)
#pragma unroll
      for (int n = 0; n < 2; n++)
        acc[m][n] = __builtin_amdgcn_mfma_f32_16x16x32_bf16(af[m], bq[n], acc[m][n], 0, 0, 0);
    __builtin_amdgcn_s_setprio(0);
    __builtin_amdgcn_s_barrier();  // buf[cur] free for the prefetch issued at t+1 top

    cur = (cur + 1 >= 3) ? 0 : cur + 1;
  }

  // epilogue: C/D layout col = lane&15 (-> gn), row = (lane>>4)*4 + j (-> gm)
#pragma unroll
  for (int m = 0; m < 8; m++) {
#pragma unroll
    for (int n = 0; n < 2; n++) {
      const int gn = bn0 + wn * 32 + n * 16 + frow;
#pragma unroll
      for (int j = 0; j < 4; j++) {
        const int gm = bm0 + wm * 128 + m * 16 + fk * 4 + j;
        const size_t off = (size_t)gm * N + gn;
        float v = acc[m][n][j];
        if (MODE == 0) {
          Ob[off] = (bf16_t)(v + bias[gn]);
        } else {  // MODE 1
          v = (float)Uin[off] + 0.1f * fast_tanh(v + bias[gn]);
          Ob[off] = (bf16_t)v;
        }
      }
    }
  }
}

// ---------------- 128^2 4-wave GEMM - kept for the N=1024 logits GEMM ----------------
__launch_bounds__(256, 2)
__global__ void k_gemm_log(const bf16_t* __restrict__ A, const bf16_t* __restrict__ Bt,
                           const float* __restrict__ bias,
                           float* __restrict__ Of,
                           int M, int N, int K, int Nvalid) {
  __shared__ bf16_t As2[128 * 64];
  __shared__ bf16_t Bs2[128 * 64];

  const int tid = threadIdx.x;
  const int lane = tid & 63;
  const int wid = tid >> 6;
  const int bn0 = blockIdx.x * 128;
  const int bm0 = blockIdx.y * 128;

  const int srow = lane >> 3;
  const int sslot = (lane & 7) ^ srow;
  const int frow = lane & 15;
  const int fk = lane >> 4;

  f32x4 acc[4][4];
#pragma unroll
  for (int m = 0; m < 4; m++)
#pragma unroll
    for (int n = 0; n < 4; n++) acc[m][n] = (f32x4){0.f, 0.f, 0.f, 0.f};

  const int wm = wid >> 1;
  const int wn = wid & 1;

  const size_t aRowBase = (size_t)(bm0 + wid * 32 + srow) * K + (size_t)sslot * 8;
  const size_t bRowBase = (size_t)(bn0 + wid * 32 + srow) * K + (size_t)sslot * 8;

  for (int kt = 0; kt < K; kt += 64) {
#pragma unroll
    for (int i = 0; i < 4; i++) {
      gld_lds16(A + aRowBase + (size_t)i * 8 * K + kt, (char*)As2 + (wid * 4 + i) * 1024);
      gld_lds16(Bt + bRowBase + (size_t)i * 8 * K + kt, (char*)Bs2 + (wid * 4 + i) * 1024);
    }
    __syncthreads();

#pragma unroll
    for (int s = 0; s < 2; s++) {
      bfrag af[4], bq[4];
#pragma unroll
      for (int m = 0; m < 4; m++) {
        int row = wm * 64 + m * 16 + frow;
        int slot = (s * 4 + fk) ^ (row & 7);
        af[m] = *reinterpret_cast<const bfrag*>((const char*)As2 + row * 128 + slot * 16);
      }
#pragma unroll
      for (int n = 0; n < 4; n++) {
        int row = wn * 64 + n * 16 + frow;
        int slot = (s * 4 + fk) ^ (row & 7);
        bq[n] = *reinterpret_cast<const bfrag*>((const char*)Bs2 + row * 128 + slot * 16);
      }
#pragma unroll
      for (int m = 0; m < 4; m++)
#pragma unroll
        for (int n = 0; n < 4; n++)
          acc[m][n] = __builtin_amdgcn_mfma_f32_16x16x32_bf16(af[m], bq[n], acc[m][n], 0, 0, 0);
    }
    __syncthreads();
  }

#pragma unroll
  for (int m = 0; m < 4; m++) {
#pragma unroll
    for (int n = 0; n < 4; n++) {
      const int gn = bn0 + wn * 64 + n * 16 + frow;
#pragma unroll
      for (int j = 0; j < 4; j++) {
        const int gm = bm0 + wm * 64 + m * 16 + fk * 4 + j;
        const size_t off = (size_t)gm * N + gn;
        if (gn < Nvalid) Of[off] = acc[m][n][j] + bias[gn];
      }
    }
  }
}

// ---------------- row softmax ----------------
__global__ void k_softmax(const float* __restrict__ logits, float* __restrict__ out) {
  __shared__ float red[256];
  const int r = blockIdx.x;
  const float* L = logits + (size_t)r * NPAD_OUT;
  float* O = out + (size_t)r * OUT_DIM;
  const int tid = threadIdx.x;

  float lmax = -INFINITY;
  for (int j = tid; j < OUT_DIM; j += 256) lmax = fmaxf(lmax, L[j]);
  red[tid] = lmax;
  __syncthreads();
  for (int s = 128; s > 0; s >>= 1) {
    if (tid < s) red[tid] = fmaxf(red[tid], red[tid + s]);
    __syncthreads();
  }
  const float rmax = red[0];
  __syncthreads();
  float lsum = 0.f;
  for (int j = tid; j < OUT_DIM; j += 256) {
    float e = expf(L[j] - rmax);
    O[j] = e;
    lsum += e;
  }
  red[tid] = lsum;
  __syncthreads();
  for (int s = 128; s > 0; s >>= 1) {
    if (tid < s) red[tid] += red[tid + s];
    __syncthreads();
  }
  const float inv = 1.0f / red[0];
  for (int j = tid; j < OUT_DIM; j += 256) O[j] *= inv;
}

extern "C" void kernel_launch(void* const* d_in, const int* in_sizes, int n_in,
                              void* d_out, int out_size, void* d_ws, size_t ws_size,
                              hipStream_t stream) {
  const float* x = (const float*)d_in[0];
  const float* W_in = (const float*)d_in[1];
  const float* b_in = (const float*)d_in[2];
  const float* W_out = (const float*)d_in[3];
  const float* b_out = (const float*)d_in[4];
  const float* W[4] = {(const float*)d_in[5], (const float*)d_in[7],
                       (const float*)d_in[9], (const float*)d_in[11]};
  const float* bb[4] = {(const float*)d_in[6], (const float*)d_in[8],
                        (const float*)d_in[10], (const float*)d_in[12]};
  float* out = (float*)d_out;

  // ---- workspace: 3x16 + 8 + 16 = 72 MiB (proven-safe footprint) ----
  char* ws = (char*)d_ws;
  size_t off = 0;
  auto alloc = [&](size_t bytes) {
    void* p = ws + off;
    off += (bytes + 255) & ~(size_t)255;
    return p;
  };
  bf16_t* B0 = (bf16_t*)alloc((size_t)BATCH * UNITS * 2);
  bf16_t* B1 = (bf16_t*)alloc((size_t)BATCH * UNITS * 2);
  bf16_t* B2 = (bf16_t*)alloc((size_t)BATCH * UNITS * 2);
  bf16_t* wt = (bf16_t*)alloc((size_t)UNITS * UNITS * 2);
  float* logits = (float*)alloc((size_t)BATCH * NPAD_OUT * 4);
  bf16_t* xb = B1;  // alias: dead before block-0 iter-0 writes B1

  dim3 tb(32, 8);
  const int g8 = (UNITS / 128) * (BATCH / 256);  // 256 blocks

  // z0 = x @ W_in + b_in  -> B0 (bf16); B0 is block 0's residual base u
  k_f32_to_bf16<<<(BATCH * IN_DIM) / 256, 256, 0, stream>>>(x, xb, BATCH * IN_DIM);
  k_transpose_bf16<<<dim3(UNITS / 32, IN_DIM / 32), tb, 0, stream>>>(W_in, wt, IN_DIM, UNITS, UNITS);
  k_gemm8<0><<<g8, 512, 0, stream>>>(xb, wt, b_in, nullptr, B0, BATCH, UNITS, IN_DIM);

  // 4 blocks x NITER: y <- u + 0.1*tanh(y @ W_b + b_b); all state bf16, 3-buffer rotation
  bf16_t* ub = B0;
  for (int b = 0; b < 4; b++) {
    k_transpose_bf16<<<dim3(UNITS / 32, UNITS / 32), tb, 0, stream>>>(W[b], wt, UNITS, UNITS, UNITS);
    bf16_t* others[2];
    int k = 0;
    if (B0 != ub) others[k++] = B0;
    if (B1 != ub) others[k++] = B1;
    if (B2 != ub) others[k++] = B2;
    bf16_t* src = ub;  // y_0 = u
    for (int t = 0; t < NITER; t++) {
      bf16_t* dst = others[t & 1];
      k_gemm8<1><<<g8, 512, 0, stream>>>(src, wt, bb[b], ub, dst, BATCH, UNITS, UNITS);
      src = dst;
    }
    ub = src;  // block output becomes next block's residual base
  }

  // logits + softmax
  k_transpose_bf16<<<dim3(NPAD_OUT / 32, UNITS / 32), tb, 0, stream>>>(W_out, wt, UNITS, OUT_DIM, NPAD_OUT);
  k_gemm_log<<<dim3(NPAD_OUT / 128, BATCH / 128), 256, 0, stream>>>(
      ub, wt, b_out, logits, BATCH, NPAD_OUT, UNITS, OUT_DIM);
  k_softmax<<<BATCH, 256, 0, stream>>>(logits, out);
}

// Round 8
// 716.491 us; speedup vs baseline: 2.7172x; 1.0829x over previous
//
#include <hip/hip_runtime.h>
#include <math.h>

#define BATCH 4096
#define IN_DIM 1024
#define UNITS 2048
#define OUT_DIM 1000
#define NPAD_OUT 1024
#define NITER 3

typedef __bf16 bf16_t;
typedef __attribute__((ext_vector_type(8))) __bf16 bfrag;
typedef __attribute__((ext_vector_type(4))) float f32x4;

typedef __attribute__((address_space(1))) void gvoid_t;
typedef __attribute__((address_space(3))) void lvoid_t;

__device__ __forceinline__ void gld_lds16(const void* g, void* l) {
  __builtin_amdgcn_global_load_lds((gvoid_t*)g, (lvoid_t*)l, 16, 0, 0);
}

// fast tanh: 1 - 2/(exp2(2*log2e*x)+1); v_exp_f32+v_rcp_f32, ~1ulp f32 (bf16-irrelevant)
__device__ __forceinline__ float fast_tanh(float x) {
  float e, r;
  asm("v_exp_f32 %0, %1" : "=v"(e) : "v"(x * 2.88539008177793f));
  asm("v_rcp_f32 %0, %1" : "=v"(r) : "v"(e + 1.0f));
  return __builtin_fmaf(-2.0f, r, 1.0f);
}

// ---------------- elementwise f32 -> bf16 ----------------
__global__ void k_f32_to_bf16(const float* __restrict__ in, bf16_t* __restrict__ out, int n) {
  int i = blockIdx.x * 256 + threadIdx.x;
  if (i < n) out[i] = (bf16_t)in[i];
}

// ---- transpose f32 (K x N, row stride N) -> bf16 (Npad x K); pads with 0 ----
__global__ void k_transpose_bf16(const float* __restrict__ src, bf16_t* __restrict__ dst,
                                 int K, int N, int Npad) {
  __shared__ float t[32][33];
  int n0 = blockIdx.x * 32;
  int k0 = blockIdx.y * 32;
  int tx = threadIdx.x, ty = threadIdx.y;  // 32 x 8
#pragma unroll
  for (int i = 0; i < 4; i++) {
    int k = k0 + ty + i * 8;
    int n = n0 + tx;
    t[ty + i * 8][tx] = (n < N) ? src[(size_t)k * N + n] : 0.0f;
  }
  __syncthreads();
#pragma unroll
  for (int i = 0; i < 4; i++) {
    int n = n0 + ty + i * 8;
    int k = k0 + tx;
    if (n < Npad) dst[(size_t)n * K + k] = (bf16_t)t[tx][ty + i * 8];
  }
}

// ======== 8-wave GEMM: C = A(MxK) * Bt(NxK)^T, BM=256 BN=128 BK=64 ========
// Triple-buffered LDS, 2-tiles-ahead prefetch, ONE barrier + vmcnt(6) per K-step,
// free-running ds_read/MFMA within the iter (cross-wave pipe overlap).
// MODE 0: Ob = bf16(acc + bias)
// MODE 1: Ob = bf16( (f32)Uin + 0.1*tanh(acc + bias) )   (all state bf16)
template <int MODE>
__launch_bounds__(512, 2)
__global__ void k_gemm8(const bf16_t* __restrict__ A, const bf16_t* __restrict__ Bt,
                        const float* __restrict__ bias, const bf16_t* __restrict__ Uin,
                        bf16_t* __restrict__ Ob,
                        int M, int N, int K) {
  __shared__ bf16_t As[3][256 * 64];  // 96 KiB
  __shared__ bf16_t Bs[3][128 * 64];  // 48 KiB

  const int tid = threadIdx.x;
  const int lane = tid & 63;
  const int wid = tid >> 6;
  const int wm = wid >> 2;  // 0..1  (M half, 128 rows)
  const int wn = wid & 3;   // 0..3  (N quarter, 32 cols)

  // XCD-aware bijective swizzle (grid % 8 == 0 here)
  const int nbx = N >> 7;  // N/128
  int bid = (int)blockIdx.x;
  const int cpx = (int)gridDim.x >> 3;
  bid = (bid & 7) * cpx + (bid >> 3);
  const int bn0 = (bid % nbx) * 128;
  const int bm0 = (bid / nbx) * 256;

  // staging: chunk = 1024B = 8 rows x 128B. lane l -> row l>>3, slot l&7 (16B units).
  // XOR swizzle via pre-swizzled GLOBAL source; LDS stays linear (rule #21).
  const int srow = lane >> 3;
  const int sslotg = (lane & 7) ^ srow;
  const size_t aBase = (size_t)(bm0 + wid * 32 + srow) * K + (size_t)sslotg * 8;
  const size_t bBase = (size_t)(bn0 + wid * 16 + srow) * K + (size_t)sslotg * 8;

  const int frow = lane & 15;
  const int fk = lane >> 4;

  f32x4 acc[8][2];
#pragma unroll
  for (int m = 0; m < 8; m++)
#pragma unroll
    for (int n = 0; n < 2; n++) acc[m][n] = (f32x4){0.f, 0.f, 0.f, 0.f};

  auto stageA = [&](int buf, int kt, int i) {
    gld_lds16(A + aBase + (size_t)i * 8 * K + kt, (char*)&As[buf][0] + (wid * 4 + i) * 1024);
  };
  auto stageB = [&](int buf, int kt, int i) {
    gld_lds16(Bt + bBase + (size_t)i * 8 * K + kt, (char*)&Bs[buf][0] + (wid * 2 + i) * 1024);
  };
  auto stageTile = [&](int buf, int kt) {
    stageA(buf, kt, 0); stageA(buf, kt, 1); stageA(buf, kt, 2); stageA(buf, kt, 3);
    stageB(buf, kt, 0); stageB(buf, kt, 1);
  };

  const int NT = K >> 6;
  // prologue: tiles 0,1 in flight (12 loads)
  stageTile(0, 0);
  stageTile(1, 64);

  const int sw = (frow & 7);
  int cur = 0;

  for (int t = 0; t < NT; ++t) {
    // wait: 12 outstanding (tiles t, t+1) -> drain to 6: tile t complete (FIFO)
    if (t + 1 < NT) {
      asm volatile("s_waitcnt vmcnt(6)" ::: "memory");
    } else {
      asm volatile("s_waitcnt vmcnt(0)" ::: "memory");
    }
    // ONE barrier: (a) all waves drained their tile-t stores -> buf[cur] visible;
    // (b) all waves done reading slot nb during iter t-1 -> safe to overwrite below.
    __builtin_amdgcn_s_barrier();
    if (t + 2 < NT) {
      const int nb = (cur + 2 >= 3) ? cur - 1 : cur + 2;
      stageTile(nb, (t + 2) << 6);
    }

    const char* pa = (const char*)&As[cur][0] + (wm * 128 + frow) * 128;
    const char* pb = (const char*)&Bs[cur][0] + (wn * 32 + frow) * 128;
    const int sl0 = ((0 + fk) ^ sw) * 16;
    const int sl1 = ((4 + fk) ^ sw) * 16;

    bfrag af[8], bq[2];
    // ---- phase A: s=0, 16 MFMA (free-running; compiler inserts fine lgkmcnt) ----
#pragma unroll
    for (int m = 0; m < 8; m++) af[m] = *reinterpret_cast<const bfrag*>(pa + m * 2048 + sl0);
    bq[0] = *reinterpret_cast<const bfrag*>(pb + sl0);
    bq[1] = *reinterpret_cast<const bfrag*>(pb + 2048 + sl0);
    __builtin_amdgcn_s_setprio(1);
#pragma unroll
    for (int m = 0; m < 8; m++)
#pragma unroll
      for (int n = 0; n < 2; n++)
        acc[m][n] = __builtin_amdgcn_mfma_f32_16x16x32_bf16(af[m], bq[n], acc[m][n], 0, 0, 0);
    __builtin_amdgcn_s_setprio(0);

    // ---- phase B: s=1, 16 MFMA ----
#pragma unroll
    for (int m = 0; m < 8; m++) af[m] = *reinterpret_cast<const bfrag*>(pa + m * 2048 + sl1);
    bq[0] = *reinterpret_cast<const bfrag*>(pb + sl1);
    bq[1] = *reinterpret_cast<const bfrag*>(pb + 2048 + sl1);
    __builtin_amdgcn_s_setprio(1);
#pragma unroll
    for (int m = 0; m < 8; m++)
#pragma unroll
      for (int n = 0; n < 2; n++)
        acc[m][n] = __builtin_amdgcn_mfma_f32_16x16x32_bf16(af[m], bq[n], acc[m][n], 0, 0, 0);
    __builtin_amdgcn_s_setprio(0);

    cur = (cur + 1 >= 3) ? 0 : cur + 1;
  }

  // epilogue: C/D layout col = lane&15 (-> gn), row = (lane>>4)*4 + j (-> gm)
#pragma unroll
  for (int m = 0; m < 8; m++) {
#pragma unroll
    for (int n = 0; n < 2; n++) {
      const int gn = bn0 + wn * 32 + n * 16 + frow;
#pragma unroll
      for (int j = 0; j < 4; j++) {
        const int gm = bm0 + wm * 128 + m * 16 + fk * 4 + j;
        const size_t off = (size_t)gm * N + gn;
        float v = acc[m][n][j];
        if (MODE == 0) {
          Ob[off] = (bf16_t)(v + bias[gn]);
        } else {  // MODE 1
          v = (float)Uin[off] + 0.1f * fast_tanh(v + bias[gn]);
          Ob[off] = (bf16_t)v;
        }
      }
    }
  }
}

// ---------------- 128^2 4-wave GEMM - kept for the N=1024 logits GEMM ----------------
__launch_bounds__(256, 2)
__global__ void k_gemm_log(const bf16_t* __restrict__ A, const bf16_t* __restrict__ Bt,
                           const float* __restrict__ bias,
                           float* __restrict__ Of,
                           int M, int N, int K, int Nvalid) {
  __shared__ bf16_t As2[128 * 64];
  __shared__ bf16_t Bs2[128 * 64];

  const int tid = threadIdx.x;
  const int lane = tid & 63;
  const int wid = tid >> 6;
  const int bn0 = blockIdx.x * 128;
  const int bm0 = blockIdx.y * 128;

  const int srow = lane >> 3;
  const int sslot = (lane & 7) ^ srow;
  const int frow = lane & 15;
  const int fk = lane >> 4;

  f32x4 acc[4][4];
#pragma unroll
  for (int m = 0; m < 4; m++)
#pragma unroll
    for (int n = 0; n < 4; n++) acc[m][n] = (f32x4){0.f, 0.f, 0.f, 0.f};

  const int wm = wid >> 1;
  const int wn = wid & 1;

  const size_t aRowBase = (size_t)(bm0 + wid * 32 + srow) * K + (size_t)sslot * 8;
  const size_t bRowBase = (size_t)(bn0 + wid * 32 + srow) * K + (size_t)sslot * 8;

  for (int kt = 0; kt < K; kt += 64) {
#pragma unroll
    for (int i = 0; i < 4; i++) {
      gld_lds16(A + aRowBase + (size_t)i * 8 * K + kt, (char*)As2 + (wid * 4 + i) * 1024);
      gld_lds16(Bt + bRowBase + (size_t)i * 8 * K + kt, (char*)Bs2 + (wid * 4 + i) * 1024);
    }
    __syncthreads();

#pragma unroll
    for (int s = 0; s < 2; s++) {
      bfrag af[4], bq[4];
#pragma unroll
      for (int m = 0; m < 4; m++) {
        int row = wm * 64 + m * 16 + frow;
        int slot = (s * 4 + fk) ^ (row & 7);
        af[m] = *reinterpret_cast<const bfrag*>((const char*)As2 + row * 128 + slot * 16);
      }
#pragma unroll
      for (int n = 0; n < 4; n++) {
        int row = wn * 64 + n * 16 + frow;
        int slot = (s * 4 + fk) ^ (row & 7);
        bq[n] = *reinterpret_cast<const bfrag*>((const char*)Bs2 + row * 128 + slot * 16);
      }
#pragma unroll
      for (int m = 0; m < 4; m++)
#pragma unroll
        for (int n = 0; n < 4; n++)
          acc[m][n] = __builtin_amdgcn_mfma_f32_16x16x32_bf16(af[m], bq[n], acc[m][n], 0, 0, 0);
    }
    __syncthreads();
  }

#pragma unroll
  for (int m = 0; m < 4; m++) {
#pragma unroll
    for (int n = 0; n < 4; n++) {
      const int gn = bn0 + wn * 64 + n * 16 + frow;
#pragma unroll
      for (int j = 0; j < 4; j++) {
        const int gm = bm0 + wm * 64 + m * 16 + fk * 4 + j;
        const size_t off = (size_t)gm * N + gn;
        if (gn < Nvalid) Of[off] = acc[m][n][j] + bias[gn];
      }
    }
  }
}

// ---------------- row softmax ----------------
__global__ void k_softmax(const float* __restrict__ logits, float* __restrict__ out) {
  __shared__ float red[256];
  const int r = blockIdx.x;
  const float* L = logits + (size_t)r * NPAD_OUT;
  float* O = out + (size_t)r * OUT_DIM;
  const int tid = threadIdx.x;

  float lmax = -INFINITY;
  for (int j = tid; j < OUT_DIM; j += 256) lmax = fmaxf(lmax, L[j]);
  red[tid] = lmax;
  __syncthreads();
  for (int s = 128; s > 0; s >>= 1) {
    if (tid < s) red[tid] = fmaxf(red[tid], red[tid + s]);
    __syncthreads();
  }
  const float rmax = red[0];
  __syncthreads();
  float lsum = 0.f;
  for (int j = tid; j < OUT_DIM; j += 256) {
    float e = expf(L[j] - rmax);
    O[j] = e;
    lsum += e;
  }
  red[tid] = lsum;
  __syncthreads();
  for (int s = 128; s > 0; s >>= 1) {
    if (tid < s) red[tid] += red[tid + s];
    __syncthreads();
  }
  const float inv = 1.0f / red[0];
  for (int j = tid; j < OUT_DIM; j += 256) O[j] *= inv;
}

extern "C" void kernel_launch(void* const* d_in, const int* in_sizes, int n_in,
                              void* d_out, int out_size, void* d_ws, size_t ws_size,
                              hipStream_t stream) {
  const float* x = (const float*)d_in[0];
  const float* W_in = (const float*)d_in[1];
  const float* b_in = (const float*)d_in[2];
  const float* W_out = (const float*)d_in[3];
  const float* b_out = (const float*)d_in[4];
  const float* W[4] = {(const float*)d_in[5], (const float*)d_in[7],
                       (const float*)d_in[9], (const float*)d_in[11]};
  const float* bb[4] = {(const float*)d_in[6], (const float*)d_in[8],
                        (const float*)d_in[10], (const float*)d_in[12]};
  float* out = (float*)d_out;

  // ---- workspace: 3x16 + 8 + 16 = 72 MiB (proven-safe footprint) ----
  char* ws = (char*)d_ws;
  size_t off = 0;
  auto alloc = [&](size_t bytes) {
    void* p = ws + off;
    off += (bytes + 255) & ~(size_t)255;
    return p;
  };
  bf16_t* B0 = (bf16_t*)alloc((size_t)BATCH * UNITS * 2);
  bf16_t* B1 = (bf16_t*)alloc((size_t)BATCH * UNITS * 2);
  bf16_t* B2 = (bf16_t*)alloc((size_t)BATCH * UNITS * 2);
  bf16_t* wt = (bf16_t*)alloc((size_t)UNITS * UNITS * 2);
  float* logits = (float*)alloc((size_t)BATCH * NPAD_OUT * 4);
  bf16_t* xb = B1;  // alias: dead before block-0 iter-0 writes B1

  dim3 tb(32, 8);
  const int g8 = (UNITS / 128) * (BATCH / 256);  // 256 blocks

  // z0 = x @ W_in + b_in  -> B0 (bf16); B0 is block 0's residual base u
  k_f32_to_bf16<<<(BATCH * IN_DIM) / 256, 256, 0, stream>>>(x, xb, BATCH * IN_DIM);
  k_transpose_bf16<<<dim3(UNITS / 32, IN_DIM / 32), tb, 0, stream>>>(W_in, wt, IN_DIM, UNITS, UNITS);
  k_gemm8<0><<<g8, 512, 0, stream>>>(xb, wt, b_in, nullptr, B0, BATCH, UNITS, IN_DIM);

  // 4 blocks x NITER: y <- u + 0.1*tanh(y @ W_b + b_b); all state bf16, 3-buffer rotation
  bf16_t* ub = B0;
  for (int b = 0; b < 4; b++) {
    k_transpose_bf16<<<dim3(UNITS / 32, UNITS / 32), tb, 0, stream>>>(W[b], wt, UNITS, UNITS, UNITS);
    bf16_t* others[2];
    int k = 0;
    if (B0 != ub) others[k++] = B0;
    if (B1 != ub) others[k++] = B1;
    if (B2 != ub) others[k++] = B2;
    bf16_t* src = ub;  // y_0 = u
    for (int t = 0; t < NITER; t++) {
      bf16_t* dst = others[t & 1];
      k_gemm8<1><<<g8, 512, 0, stream>>>(src, wt, bb[b], ub, dst, BATCH, UNITS, UNITS);
      src = dst;
    }
    ub = src;  // block output becomes next block's residual base
  }

  // logits + softmax
  k_transpose_bf16<<<dim3(NPAD_OUT / 32, UNITS / 32), tb, 0, stream>>>(W_out, wt, UNITS, OUT_DIM, NPAD_OUT);
  k_gemm_log<<<dim3(NPAD_OUT / 128, BATCH / 128), 256, 0, stream>>>(
      ub, wt, b_out, logits, BATCH, NPAD_OUT, UNITS, OUT_DIM);
  k_softmax<<<BATCH, 256, 0, stream>>>(logits, out);
}

// Round 9
// 591.806 us; speedup vs baseline: 3.2896x; 1.2107x over previous
//
#include <hip/hip_runtime.h>
#include <math.h>

#define BATCH 4096
#define IN_DIM 1024
#define UNITS 2048
#define OUT_DIM 1000
#define NPAD_OUT 1024
#define NITER 3

typedef __bf16 bf16_t;
typedef __attribute__((ext_vector_type(8))) __bf16 bfrag;
typedef __attribute__((ext_vector_type(4))) float f32x4;

typedef __attribute__((address_space(1))) void gvoid_t;
typedef __attribute__((address_space(3))) void lvoid_t;

__device__ __forceinline__ void gld_lds16(const void* g, void* l) {
  __builtin_amdgcn_global_load_lds((gvoid_t*)g, (lvoid_t*)l, 16, 0, 0);
}

// fast tanh: 1 - 2/(exp2(2*log2e*x)+1); v_exp_f32+v_rcp_f32, ~1ulp f32 (bf16-irrelevant)
__device__ __forceinline__ float fast_tanh(float x) {
  float e, r;
  asm("v_exp_f32 %0, %1" : "=v"(e) : "v"(x * 2.88539008177793f));
  asm("v_rcp_f32 %0, %1" : "=v"(r) : "v"(e + 1.0f));
  return __builtin_fmaf(-2.0f, r, 1.0f);
}

// ---------------- elementwise f32 -> bf16 ----------------
__global__ void k_f32_to_bf16(const float* __restrict__ in, bf16_t* __restrict__ out, int n) {
  int i = blockIdx.x * 256 + threadIdx.x;
  if (i < n) out[i] = (bf16_t)in[i];
}

// ---- transpose f32 (K x N, row stride N) -> bf16 (Npad x K); pads with 0 ----
__global__ void k_transpose_bf16(const float* __restrict__ src, bf16_t* __restrict__ dst,
                                 int K, int N, int Npad) {
  __shared__ float t[32][33];
  int n0 = blockIdx.x * 32;
  int k0 = blockIdx.y * 32;
  int tx = threadIdx.x, ty = threadIdx.y;  // 32 x 8
#pragma unroll
  for (int i = 0; i < 4; i++) {
    int k = k0 + ty + i * 8;
    int n = n0 + tx;
    t[ty + i * 8][tx] = (n < N) ? src[(size_t)k * N + n] : 0.0f;
  }
  __syncthreads();
#pragma unroll
  for (int i = 0; i < 4; i++) {
    int n = n0 + ty + i * 8;
    int k = k0 + tx;
    if (n < Npad) dst[(size_t)n * K + k] = (bf16_t)t[tx][ty + i * 8];
  }
}

// ======== 128^2 4-wave GEMM (m97 structure, session-verified): C = A * Bt^T ========
// 32KB LDS single buffer -> 4-5 blocks/CU; cross-block TLP overlaps LDS & MFMA pipes.
// MODE 0: Ob = bf16(acc + bias)
// MODE 1: Ob = bf16( (f32)Uin + 0.1*tanh(acc + bias) )   (all state bf16)
// MODE 3: Of = acc + bias, only cols < Nvalid (f32 logits)
template <int MODE>
__launch_bounds__(256, 2)
__global__ void k_gemm128(const bf16_t* __restrict__ A, const bf16_t* __restrict__ Bt,
                          const float* __restrict__ bias, const bf16_t* __restrict__ Uin,
                          bf16_t* __restrict__ Ob, float* __restrict__ Of,
                          int M, int N, int K, int Nvalid) {
  __shared__ bf16_t As2[128 * 64];
  __shared__ bf16_t Bs2[128 * 64];

  const int tid = threadIdx.x;
  const int lane = tid & 63;
  const int wid = tid >> 6;

  // XCD-aware bijective swizzle (grid % 8 == 0 for all our launches)
  int bid = (int)blockIdx.x;
  const int cpx = (int)gridDim.x >> 3;
  bid = (bid & 7) * cpx + (bid >> 3);
  const int nbx = N >> 7;
  const int bn0 = (bid % nbx) * 128;
  const int bm0 = (bid / nbx) * 128;

  const int srow = lane >> 3;
  const int sslot = (lane & 7) ^ srow;  // XOR swizzle via pre-swizzled global source
  const int frow = lane & 15;
  const int fk = lane >> 4;

  f32x4 acc[4][4];
#pragma unroll
  for (int m = 0; m < 4; m++)
#pragma unroll
    for (int n = 0; n < 4; n++) acc[m][n] = (f32x4){0.f, 0.f, 0.f, 0.f};

  const int wm = wid >> 1;
  const int wn = wid & 1;

  const size_t aRowBase = (size_t)(bm0 + wid * 32 + srow) * K + (size_t)sslot * 8;
  const size_t bRowBase = (size_t)(bn0 + wid * 32 + srow) * K + (size_t)sslot * 8;

  for (int kt = 0; kt < K; kt += 64) {
#pragma unroll
    for (int i = 0; i < 4; i++) {
      gld_lds16(A + aRowBase + (size_t)i * 8 * K + kt, (char*)As2 + (wid * 4 + i) * 1024);
      gld_lds16(Bt + bRowBase + (size_t)i * 8 * K + kt, (char*)Bs2 + (wid * 4 + i) * 1024);
    }
    __syncthreads();

#pragma unroll
    for (int s = 0; s < 2; s++) {
      bfrag af[4], bq[4];
#pragma unroll
      for (int m = 0; m < 4; m++) {
        int row = wm * 64 + m * 16 + frow;
        int slot = (s * 4 + fk) ^ (row & 7);
        af[m] = *reinterpret_cast<const bfrag*>((const char*)As2 + row * 128 + slot * 16);
      }
#pragma unroll
      for (int n = 0; n < 4; n++) {
        int row = wn * 64 + n * 16 + frow;
        int slot = (s * 4 + fk) ^ (row & 7);
        bq[n] = *reinterpret_cast<const bfrag*>((const char*)Bs2 + row * 128 + slot * 16);
      }
#pragma unroll
      for (int m = 0; m < 4; m++)
#pragma unroll
        for (int n = 0; n < 4; n++)
          acc[m][n] = __builtin_amdgcn_mfma_f32_16x16x32_bf16(af[m], bq[n], acc[m][n], 0, 0, 0);
    }
    __syncthreads();
  }

  // epilogue: C/D layout col = lane&15 (-> gn), row = (lane>>4)*4 + j (-> gm)
#pragma unroll
  for (int m = 0; m < 4; m++) {
#pragma unroll
    for (int n = 0; n < 4; n++) {
      const int gn = bn0 + wn * 64 + n * 16 + frow;
#pragma unroll
      for (int j = 0; j < 4; j++) {
        const int gm = bm0 + wm * 64 + m * 16 + fk * 4 + j;
        const size_t off = (size_t)gm * N + gn;
        float v = acc[m][n][j];
        if (MODE == 0) {
          Ob[off] = (bf16_t)(v + bias[gn]);
        } else if (MODE == 1) {
          v = (float)Uin[off] + 0.1f * fast_tanh(v + bias[gn]);
          Ob[off] = (bf16_t)v;
        } else {  // MODE 3
          if (gn < Nvalid) Of[off] = v + bias[gn];
        }
      }
    }
  }
}

// ---------------- row softmax ----------------
__global__ void k_softmax(const float* __restrict__ logits, float* __restrict__ out) {
  __shared__ float red[256];
  const int r = blockIdx.x;
  const float* L = logits + (size_t)r * NPAD_OUT;
  float* O = out + (size_t)r * OUT_DIM;
  const int tid = threadIdx.x;

  float lmax = -INFINITY;
  for (int j = tid; j < OUT_DIM; j += 256) lmax = fmaxf(lmax, L[j]);
  red[tid] = lmax;
  __syncthreads();
  for (int s = 128; s > 0; s >>= 1) {
    if (tid < s) red[tid] = fmaxf(red[tid], red[tid + s]);
    __syncthreads();
  }
  const float rmax = red[0];
  __syncthreads();
  float lsum = 0.f;
  for (int j = tid; j < OUT_DIM; j += 256) {
    float e = expf(L[j] - rmax);
    O[j] = e;
    lsum += e;
  }
  red[tid] = lsum;
  __syncthreads();
  for (int s = 128; s > 0; s >>= 1) {
    if (tid < s) red[tid] += red[tid + s];
    __syncthreads();
  }
  const float inv = 1.0f / red[0];
  for (int j = tid; j < OUT_DIM; j += 256) O[j] *= inv;
}

extern "C" void kernel_launch(void* const* d_in, const int* in_sizes, int n_in,
                              void* d_out, int out_size, void* d_ws, size_t ws_size,
                              hipStream_t stream) {
  const float* x = (const float*)d_in[0];
  const float* W_in = (const float*)d_in[1];
  const float* b_in = (const float*)d_in[2];
  const float* W_out = (const float*)d_in[3];
  const float* b_out = (const float*)d_in[4];
  const float* W[4] = {(const float*)d_in[5], (const float*)d_in[7],
                       (const float*)d_in[9], (const float*)d_in[11]};
  const float* bb[4] = {(const float*)d_in[6], (const float*)d_in[8],
                        (const float*)d_in[10], (const float*)d_in[12]};
  float* out = (float*)d_out;

  // ---- workspace: 3x16 + 8 + 16 = 72 MiB (proven-safe footprint) ----
  char* ws = (char*)d_ws;
  size_t off = 0;
  auto alloc = [&](size_t bytes) {
    void* p = ws + off;
    off += (bytes + 255) & ~(size_t)255;
    return p;
  };
  bf16_t* B0 = (bf16_t*)alloc((size_t)BATCH * UNITS * 2);
  bf16_t* B1 = (bf16_t*)alloc((size_t)BATCH * UNITS * 2);
  bf16_t* B2 = (bf16_t*)alloc((size_t)BATCH * UNITS * 2);
  bf16_t* wt = (bf16_t*)alloc((size_t)UNITS * UNITS * 2);
  float* logits = (float*)alloc((size_t)BATCH * NPAD_OUT * 4);
  bf16_t* xb = B1;  // alias: dead before block-0 iter-0 writes B1

  dim3 tb(32, 8);
  const int g_iter = (UNITS / 128) * (BATCH / 128);     // 16*32 = 512 blocks (%8==0)
  const int g_log = (NPAD_OUT / 128) * (BATCH / 128);   // 8*32 = 256 blocks (%8==0)

  // z0 = x @ W_in + b_in  -> B0 (bf16); B0 is block 0's residual base u
  k_f32_to_bf16<<<(BATCH * IN_DIM) / 256, 256, 0, stream>>>(x, xb, BATCH * IN_DIM);
  k_transpose_bf16<<<dim3(UNITS / 32, IN_DIM / 32), tb, 0, stream>>>(W_in, wt, IN_DIM, UNITS, UNITS);
  k_gemm128<0><<<g_iter, 256, 0, stream>>>(xb, wt, b_in, nullptr, B0, nullptr,
                                           BATCH, UNITS, IN_DIM, UNITS);

  // 4 blocks x NITER: y <- u + 0.1*tanh(y @ W_b + b_b); all state bf16, 3-buffer rotation
  bf16_t* ub = B0;
  for (int b = 0; b < 4; b++) {
    k_transpose_bf16<<<dim3(UNITS / 32, UNITS / 32), tb, 0, stream>>>(W[b], wt, UNITS, UNITS, UNITS);
    bf16_t* others[2];
    int k = 0;
    if (B0 != ub) others[k++] = B0;
    if (B1 != ub) others[k++] = B1;
    if (B2 != ub) others[k++] = B2;
    bf16_t* src = ub;  // y_0 = u
    for (int t = 0; t < NITER; t++) {
      bf16_t* dst = others[t & 1];
      k_gemm128<1><<<g_iter, 256, 0, stream>>>(src, wt, bb[b], ub, dst, nullptr,
                                               BATCH, UNITS, UNITS, UNITS);
      src = dst;
    }
    ub = src;  // block output becomes next block's residual base
  }

  // logits + softmax
  k_transpose_bf16<<<dim3(NPAD_OUT / 32, UNITS / 32), tb, 0, stream>>>(W_out, wt, UNITS, OUT_DIM, NPAD_OUT);
  k_gemm128<3><<<g_log, 256, 0, stream>>>(ub, wt, b_out, nullptr, nullptr, logits,
                                          BATCH, NPAD_OUT, UNITS, OUT_DIM);
  k_softmax<<<BATCH, 256, 0, stream>>>(logits, out);
}